// Round 1
// baseline (669.307 us; speedup 1.0000x reference)
//
#include <hip/hip_runtime.h>
#include <stdint.h>

typedef __attribute__((ext_vector_type(8))) short bf16x8;
typedef __attribute__((ext_vector_type(4))) float f32x4;

__device__ __forceinline__ short f2bf(float f) {
    union { float f; unsigned u; } v; v.f = f;
    unsigned r = v.u + 0x7fffu + ((v.u >> 16) & 1u);
    return (short)(r >> 16);
}
__device__ __forceinline__ float bf2f(short s) {
    union { unsigned u; float f; } v;
    v.u = ((unsigned)(unsigned short)s) << 16;
    return v.f;
}

__device__ __forceinline__ void gld16(const void* g, void* l) {
    auto gp = reinterpret_cast<const __attribute__((address_space(1))) unsigned int*>(
        reinterpret_cast<uintptr_t>(g));
    auto lp = reinterpret_cast<__attribute__((address_space(3))) unsigned int*>(
        reinterpret_cast<uintptr_t>(l));
    __builtin_amdgcn_global_load_lds(gp, lp, 16, 0, 0);
}

// ---------------------------------------------------------------------------
// NT GEMM: C[M,N] = scale * (A[M,K] @ B[N,K]^T) (+bias) (+relu)
// A,B bf16 (short bit pattern), C fp32 or bf16. 128x128 tile, BK=32,
// 4 waves each computing 64x64 via 4x4 mfma_f32_16x16x32_bf16 fragments.
// Requires M%128==0, N%128==0, K%32==0 (true for all shapes here).
// ---------------------------------------------------------------------------
template<int OUTBF, int BIASMODE /*0 none,1 col,2 row*/, int DORELU>
__global__ __launch_bounds__(256) void gemm_nt(
    const short* __restrict__ Ag, const short* __restrict__ Bg,
    void* __restrict__ Cg, const float* __restrict__ bias,
    int K, int N, long long sA, long long sB, long long sC, float scale)
{
    __shared__ short lA[128 * 32];
    __shared__ short lB[128 * 32];
    const int t = threadIdx.x;
    const int lane = t & 63;
    const int wave = t >> 6;
    const int wr = (wave >> 1) * 64;
    const int wc = (wave & 1) * 64;
    const long long row0 = (long long)blockIdx.y * 128;
    const long long col0 = (long long)blockIdx.x * 128;
    const short* Ab = Ag + (long long)blockIdx.z * sA + (row0 + (t >> 2)) * (long long)K + (t & 3) * 8;
    const short* Bb = Bg + (long long)blockIdx.z * sB + (col0 + (t >> 2)) * (long long)K + (t & 3) * 8;
    const int frow = lane & 15;
    const int fk = (lane >> 4) * 8;

    f32x4 acc[4][4] = {};
    for (int k0 = 0; k0 < K; k0 += 32) {
        if (k0) __syncthreads();
        gld16(Ab + k0, &lA[t * 8]);
        gld16(Ab + 64LL * K + k0, &lA[2048 + t * 8]);
        gld16(Bb + k0, &lB[t * 8]);
        gld16(Bb + 64LL * K + k0, &lB[2048 + t * 8]);
        __syncthreads();
        bf16x8 af[4], bb[4];
#pragma unroll
        for (int m = 0; m < 4; ++m)
            af[m] = *(const bf16x8*)&lA[(wr + m * 16 + frow) * 32 + fk];
#pragma unroll
        for (int n = 0; n < 4; ++n)
            bb[n] = *(const bf16x8*)&lB[(wc + n * 16 + frow) * 32 + fk];
#pragma unroll
        for (int m = 0; m < 4; ++m)
#pragma unroll
            for (int n = 0; n < 4; ++n)
                acc[m][n] = __builtin_amdgcn_mfma_f32_16x16x32_bf16(af[m], bb[n], acc[m][n], 0, 0, 0);
    }

    const int crow = (lane >> 4) * 4;
    const int ccol = lane & 15;
    const long long cz = (long long)blockIdx.z * sC;
#pragma unroll
    for (int m = 0; m < 4; ++m)
#pragma unroll
        for (int n = 0; n < 4; ++n)
#pragma unroll
            for (int i = 0; i < 4; ++i) {
                long long r = row0 + wr + m * 16 + crow + i;
                long long c = col0 + wc + n * 16 + ccol;
                float v = acc[m][n][i] * scale;
                if (BIASMODE == 1) v += bias[c];
                if (BIASMODE == 2) v += bias[r];
                if (DORELU) v = fmaxf(v, 0.0f);
                long long idx = cz + r * (long long)N + c;
                if (OUTBF) ((short*)Cg)[idx] = f2bf(v);
                else ((float*)Cg)[idx] = v;
            }
}

// fp32 -> bf16 straight cast
__global__ __launch_bounds__(256) void cast_kernel(
    const float* __restrict__ in, short* __restrict__ out, long long n)
{
    long long i = ((long long)blockIdx.x * 256 + threadIdx.x) * 4;
    if (i + 3 < n) {
        float4 v = *(const float4*)&in[i];
        short4 o;
        o.x = f2bf(v.x); o.y = f2bf(v.y); o.z = f2bf(v.z); o.w = f2bf(v.w);
        *(short4*)&out[i] = o;
    }
}

// fp32 [R,C] -> bf16 [C,R], per-batch strides. 64x64 LDS tile.
__global__ __launch_bounds__(256) void transpose_cast(
    const float* __restrict__ in, short* __restrict__ out,
    int R, int C, long long sIn, long long sOut)
{
    __shared__ float tile[64][65];
    const long long zi = (long long)blockIdx.z * sIn;
    const long long zo = (long long)blockIdx.z * sOut;
    const int r0 = blockIdx.y * 64, c0 = blockIdx.x * 64;
    const int lr = threadIdx.x >> 6, lc = threadIdx.x & 63;
#pragma unroll
    for (int i = 0; i < 16; ++i) {
        int r = lr * 16 + i;
        tile[r][lc] = in[zi + (long long)(r0 + r) * C + c0 + lc];
    }
    __syncthreads();
#pragma unroll
    for (int i = 0; i < 16; ++i) {
        int r = lr * 16 + i;
        out[zo + (long long)(c0 + r) * R + r0 + lc] = f2bf(tile[lc][r]);
    }
}

// blended dual softmax over rows of length 2048:
// score = a1*softmax(mixed) + (1-a1)*softmax(att); write fp32 + bf16 copies
__global__ __launch_bounds__(256) void softmax_blend(
    const short* __restrict__ attb, const short* __restrict__ mixb,
    const float* __restrict__ a1p,
    float* __restrict__ outF, short* __restrict__ outB)
{
    const int S = 2048;
    const long long row = blockIdx.x;
    const short* ar = attb + row * S;
    const short* mr = mixb + row * S;
    const int t = threadIdx.x;
    const int wave = t >> 6;

    bf16x8 a8 = *(const bf16x8*)&ar[t * 8];
    bf16x8 m8 = *(const bf16x8*)&mr[t * 8];
    float av[8], mv[8];
#pragma unroll
    for (int i = 0; i < 8; ++i) { av[i] = bf2f(a8[i]); mv[i] = bf2f(m8[i]); }

    float amax = av[0], mmax = mv[0];
#pragma unroll
    for (int i = 1; i < 8; ++i) { amax = fmaxf(amax, av[i]); mmax = fmaxf(mmax, mv[i]); }
#pragma unroll
    for (int o = 32; o; o >>= 1) {
        amax = fmaxf(amax, __shfl_xor(amax, o));
        mmax = fmaxf(mmax, __shfl_xor(mmax, o));
    }
    __shared__ float red[2][4];
    if ((t & 63) == 0) { red[0][wave] = amax; red[1][wave] = mmax; }
    __syncthreads();
    amax = fmaxf(fmaxf(red[0][0], red[0][1]), fmaxf(red[0][2], red[0][3]));
    mmax = fmaxf(fmaxf(red[1][0], red[1][1]), fmaxf(red[1][2], red[1][3]));

    float asum = 0.f, msum = 0.f;
#pragma unroll
    for (int i = 0; i < 8; ++i) {
        av[i] = __expf(av[i] - amax); asum += av[i];
        mv[i] = __expf(mv[i] - mmax); msum += mv[i];
    }
#pragma unroll
    for (int o = 32; o; o >>= 1) {
        asum += __shfl_xor(asum, o);
        msum += __shfl_xor(msum, o);
    }
    __shared__ float red2[2][4];
    if ((t & 63) == 0) { red2[0][wave] = asum; red2[1][wave] = msum; }
    __syncthreads();
    asum = red2[0][0] + red2[0][1] + red2[0][2] + red2[0][3];
    msum = red2[1][0] + red2[1][1] + red2[1][2] + red2[1][3];

    const float a1 = a1p[0];
    const float wm = a1 / msum;
    const float wa = (1.0f - a1) / asum;

    float o0[8];
    bf16x8 ob;
#pragma unroll
    for (int i = 0; i < 8; ++i) {
        float s = wm * mv[i] + wa * av[i];
        o0[i] = s;
        ob[i] = f2bf(s);
    }
    float4 f0, f1;
    f0.x = o0[0]; f0.y = o0[1]; f0.z = o0[2]; f0.w = o0[3];
    f1.x = o0[4]; f1.y = o0[5]; f1.z = o0[6]; f1.w = o0[7];
    *(float4*)&outF[row * S + t * 8] = f0;
    *(float4*)&outF[row * S + t * 8 + 4] = f1;
    *(bf16x8*)&outB[row * S + t * 8] = ob;
}

// LayerNorm over D=384 of (X + Yr); one wave per row, 4 rows/block
template<int WRITE_BF>
__global__ __launch_bounds__(256) void ln_kernel(
    const float* __restrict__ X, const float* __restrict__ Yr,
    const float* __restrict__ g, const float* __restrict__ be,
    float* __restrict__ outF, short* __restrict__ outB)
{
    const int Dm = 384;
    const int wave = threadIdx.x >> 6, lane = threadIdx.x & 63;
    const long long row = (long long)blockIdx.x * 4 + wave;
    const float* x = X + row * Dm;
    const float* y = Yr + row * Dm;
    float h[6];
    float s = 0.f, s2 = 0.f;
#pragma unroll
    for (int j = 0; j < 6; ++j) {
        int c = j * 64 + lane;
        h[j] = x[c] + y[c];
        s += h[j]; s2 += h[j] * h[j];
    }
#pragma unroll
    for (int o = 32; o; o >>= 1) { s += __shfl_xor(s, o); s2 += __shfl_xor(s2, o); }
    const float mean = s * (1.0f / 384.0f);
    const float var = s2 * (1.0f / 384.0f) - mean * mean;
    const float rstd = rsqrtf(var + 1e-5f);
#pragma unroll
    for (int j = 0; j < 6; ++j) {
        int c = j * 64 + lane;
        float v = (h[j] - mean) * rstd * g[c] + be[c];
        outF[row * Dm + c] = v;
        if (WRITE_BF) outB[row * Dm + c] = f2bf(v);
    }
}

extern "C" void kernel_launch(void* const* d_in, const int* in_sizes, int n_in,
                              void* d_out, int out_size, void* d_ws, size_t ws_size,
                              hipStream_t stream) {
    const float* tgt     = (const float*)d_in[0];
    const float* memory  = (const float*)d_in[1];
    const float* a1      = (const float*)d_in[2];
    const float* score_c = (const float*)d_in[3];
    const float* out_c   = (const float*)d_in[4];
    const float* Wq = (const float*)d_in[5];  const float* bq = (const float*)d_in[6];
    const float* Wk = (const float*)d_in[7];  const float* bk = (const float*)d_in[8];
    const float* Wv = (const float*)d_in[9];  const float* bv = (const float*)d_in[10];
    const float* Wu = (const float*)d_in[11]; const float* bu = (const float*)d_in[12];
    const float* Wn = (const float*)d_in[13]; const float* bn = (const float*)d_in[14];
    const float* W1 = (const float*)d_in[15]; const float* b1 = (const float*)d_in[16];
    const float* W2 = (const float*)d_in[17]; const float* b2 = (const float*)d_in[18];
    const float* g1 = (const float*)d_in[19]; const float* be1 = (const float*)d_in[20];
    const float* g2 = (const float*)d_in[21]; const float* be2 = (const float*)d_in[22];

    const long long BT = 16384;            // B*T
    const long long S2 = 2048LL * 2048;    // per-batch score matrix elems
    char* ws = (char*)d_ws;
    size_t off = 0;
    auto A_ = [&](size_t b) { size_t r = off; off += (b + 255) & ~(size_t)255; return r; };

    const size_t oTgtB = A_(BT * 384 * 2);
    const size_t oMemB = A_(BT * 256 * 2);
    const size_t oOutcB = A_(BT * 384 * 2);
    const size_t oWqT = A_(384 * 384 * 2);
    const size_t oWuT = A_(384 * 384 * 2);
    const size_t oWnT = A_(384 * 384 * 2);
    const size_t oWkT = A_(384 * 256 * 2);
    const size_t oWvT = A_(384 * 256 * 2);
    const size_t oW1T = A_(1536 * 384 * 2);
    const size_t oW2T = A_(384 * 1536 * 2);
    const size_t oQ   = A_(BT * 384 * 2);
    const size_t oK   = A_(BT * 384 * 2);
    const size_t oVT  = A_(8LL * 384 * 2048 * 2);
    const size_t oUnk = A_(BT * 384 * 2);
    const size_t oKno = A_(BT * 384 * 2);
    const size_t oJ   = A_(8 * S2 * 2);   // score1_bf, later score_bf
    const size_t oKr  = A_(8 * S2 * 2);   // score_c^T bf16, later z fp32
    const size_t oL   = A_(8 * S2 * 2);   // att_bf, later h_bf
    const size_t oM   = A_(8 * S2 * 2);   // mixed_bf, later ff fp32
    const size_t oX   = A_(BT * 384 * 4);
    const size_t oXB  = A_(BT * 384 * 2);

    short* tgt_bf  = (short*)(ws + oTgtB);
    short* mem_bf  = (short*)(ws + oMemB);
    short* outc_bf = (short*)(ws + oOutcB);
    short* WqT = (short*)(ws + oWqT);
    short* WuT = (short*)(ws + oWuT);
    short* WnT = (short*)(ws + oWnT);
    short* WkT = (short*)(ws + oWkT);
    short* WvT = (short*)(ws + oWvT);
    short* W1T = (short*)(ws + oW1T);
    short* W2T = (short*)(ws + oW2T);
    short* q_bf  = (short*)(ws + oQ);
    short* k_bf  = (short*)(ws + oK);
    short* vT_bf = (short*)(ws + oVT);
    short* unk_bf = (short*)(ws + oUnk);
    short* kno_bf = (short*)(ws + oKno);
    short* sc1_bf = (short*)(ws + oJ);
    short* score_bf = (short*)(ws + oJ);     // alias (score1 dead after mixed)
    short* scoreCt = (short*)(ws + oKr);
    float* z_f = (float*)(ws + oKr);         // alias (score_c^T dead after mixed)
    short* att_bf = (short*)(ws + oL);
    short* h_bf = (short*)(ws + oL);         // alias (att dead after blend)
    short* mix_bf = (short*)(ws + oM);
    float* ff_f = (float*)(ws + oM);         // alias (mixed dead after blend)
    float* x_f = (float*)(ws + oX);
    short* x_bf = (short*)(ws + oXB);

    float* outMain = (float*)d_out;
    float* outScore = (float*)d_out + 6291456;   // B*T*D elements

    const float SC = 0.05103103630798288f;  // 1/sqrt(384)
    dim3 blk(256);

    // casts
    cast_kernel<<<6144, blk, 0, stream>>>(tgt, tgt_bf, BT * 384);
    cast_kernel<<<4096, blk, 0, stream>>>(memory, mem_bf, BT * 256);
    cast_kernel<<<6144, blk, 0, stream>>>(out_c, outc_bf, BT * 384);
    // weight transposes ([K,N] -> [N,K] bf16)
    transpose_cast<<<dim3(6, 6, 1), blk, 0, stream>>>(Wq, WqT, 384, 384, 0, 0);
    transpose_cast<<<dim3(6, 4, 1), blk, 0, stream>>>(Wk, WkT, 256, 384, 0, 0);
    transpose_cast<<<dim3(6, 4, 1), blk, 0, stream>>>(Wv, WvT, 256, 384, 0, 0);
    transpose_cast<<<dim3(6, 6, 1), blk, 0, stream>>>(Wu, WuT, 384, 384, 0, 0);
    transpose_cast<<<dim3(6, 6, 1), blk, 0, stream>>>(Wn, WnT, 384, 384, 0, 0);
    transpose_cast<<<dim3(24, 6, 1), blk, 0, stream>>>(W1, W1T, 384, 1536, 0, 0);
    transpose_cast<<<dim3(6, 24, 1), blk, 0, stream>>>(W2, W2T, 1536, 384, 0, 0);
    // score_c^T per batch
    transpose_cast<<<dim3(32, 32, 8), blk, 0, stream>>>(score_c, scoreCt, 2048, 2048, S2, S2);

    // projections (bf16 out)
    gemm_nt<1, 1, 0><<<dim3(3, 128, 1), blk, 0, stream>>>(tgt_bf, WqT, q_bf, bq, 384, 384, 0, 0, 0, 1.0f);
    gemm_nt<1, 1, 0><<<dim3(3, 128, 1), blk, 0, stream>>>(mem_bf, WkT, k_bf, bk, 256, 384, 0, 0, 0, 1.0f);
    gemm_nt<1, 2, 0><<<dim3(16, 3, 8), blk, 0, stream>>>(WvT, mem_bf, vT_bf, bv, 256, 2048,
                                                         0, 2048LL * 256, 384LL * 2048, 1.0f);
    gemm_nt<1, 1, 0><<<dim3(3, 128, 1), blk, 0, stream>>>(tgt_bf, WuT, unk_bf, bu, 384, 384, 0, 0, 0, 1.0f);
    gemm_nt<1, 1, 0><<<dim3(3, 128, 1), blk, 0, stream>>>(outc_bf, WnT, kno_bf, bn, 384, 384, 0, 0, 0, 1.0f);

    // att = scale * q k^T ; score1 = scale * unknow know^T  (both bf16 out)
    gemm_nt<1, 0, 0><<<dim3(16, 16, 8), blk, 0, stream>>>(q_bf, k_bf, att_bf, nullptr, 384, 2048,
                                                          2048LL * 384, 2048LL * 384, S2, SC);
    gemm_nt<1, 0, 0><<<dim3(16, 16, 8), blk, 0, stream>>>(unk_bf, kno_bf, sc1_bf, nullptr, 384, 2048,
                                                          2048LL * 384, 2048LL * 384, S2, SC);
    // mixed = score1 @ score_c
    gemm_nt<1, 0, 0><<<dim3(16, 16, 8), blk, 0, stream>>>(sc1_bf, scoreCt, mix_bf, nullptr, 2048, 2048,
                                                          S2, S2, S2, 1.0f);
    // score = a1*softmax(mixed) + (1-a1)*softmax(att)
    softmax_blend<<<16384, blk, 0, stream>>>(att_bf, mix_bf, a1, outScore, score_bf);
    // z = score @ v
    gemm_nt<0, 0, 0><<<dim3(3, 16, 8), blk, 0, stream>>>(score_bf, vT_bf, z_f, nullptr, 2048, 384,
                                                         S2, 384LL * 2048, 2048LL * 384, 1.0f);
    // x = LN(tgt + z)
    ln_kernel<1><<<4096, blk, 0, stream>>>(tgt, z_f, g1, be1, x_f, x_bf);
    // FFN
    gemm_nt<1, 1, 1><<<dim3(12, 128, 1), blk, 0, stream>>>(x_bf, W1T, h_bf, b1, 384, 1536, 0, 0, 0, 1.0f);
    gemm_nt<0, 1, 0><<<dim3(3, 128, 1), blk, 0, stream>>>(h_bf, W2T, ff_f, b2, 1536, 384, 0, 0, 0, 1.0f);
    // out = LN(x + ff)
    ln_kernel<0><<<4096, blk, 0, stream>>>(x_f, ff_f, g2, be2, outMain, nullptr);
}

// Round 2
// 628.821 us; speedup vs baseline: 1.0644x; 1.0644x over previous
//
#include <hip/hip_runtime.h>
#include <stdint.h>

typedef __attribute__((ext_vector_type(8))) short bf16x8;
typedef __attribute__((ext_vector_type(4))) float f32x4;

__device__ __forceinline__ short f2bf(float f) {
    union { float f; unsigned u; } v; v.f = f;
    unsigned r = v.u + 0x7fffu + ((v.u >> 16) & 1u);
    return (short)(r >> 16);
}
__device__ __forceinline__ float bf2f(short s) {
    union { unsigned u; float f; } v;
    v.u = ((unsigned)(unsigned short)s) << 16;
    return v.f;
}

__device__ __forceinline__ void gld16(const void* g, void* l) {
    auto gp = reinterpret_cast<const __attribute__((address_space(1))) unsigned int*>(
        reinterpret_cast<uintptr_t>(g));
    auto lp = reinterpret_cast<__attribute__((address_space(3))) unsigned int*>(
        reinterpret_cast<uintptr_t>(l));
    __builtin_amdgcn_global_load_lds(gp, lp, 16, 0, 0);
}

// ---------------------------------------------------------------------------
// 256x256 NT GEMM, BK=32, 8 waves (2Mx4N), 3-buffer LDS ring, counted vmcnt,
// per-phase barrier+setprio schedule, 2-way (free) LDS bank swizzle.
// C[M,N] = scale*(A[M,K] @ B[N,K]^T) (+bias)(+relu). M%256==0, N%256==0, K%32==0, K>=64.
// ---------------------------------------------------------------------------
template<int OUTBF, int BIASMODE /*0 none,1 col*/, int DORELU>
__global__ __launch_bounds__(512, 2) void gemm256(
    const short* __restrict__ Ag, const short* __restrict__ Bg,
    void* __restrict__ Cg, const float* __restrict__ bias,
    int K, int N, long long sA, long long sB, long long sC, float scale)
{
    __shared__ short lds[3 * 16384];   // per buf: A[256][32] (8192) + B[256][32] (8192)
    const int t = threadIdx.x;
    const int lane = t & 63;
    const int wid = t >> 6;
    const int wm = wid >> 2, wn = wid & 3;
    const long long row0 = (long long)blockIdx.y * 256;
    const long long col0 = (long long)blockIdx.x * 256;
    const int NT = K >> 5;

    // staging: thread t covers segs t and 512+t of each 1024-seg (row,ks) tile.
    // seg: row=seg>>2, ks=seg&3. LDS dest LINEAR; source k pre-swizzled so that
    // swizzled reads (byte ^= ((row>>1)&3)<<4) see the right data.
    const int srow = t >> 2;           // 0..127 (seg 512+t -> row srow+128, same swizzle)
    const int sks = t & 3;
    const int gk = (sks ^ ((srow >> 1) & 3)) * 8;
    const short* Asrc = Ag + (long long)blockIdx.z * sA + (row0 + srow) * (long long)K + gk;
    const short* Bsrc = Bg + (long long)blockIdx.z * sB + (col0 + srow) * (long long)K + gk;
    const long long off128 = 128LL * K;

    const int frow = lane & 15;
    const int fq = lane >> 4;

    f32x4 acc[8][4] = {};

#define STAGE_A(BUF, KT) do { \
        gld16(Asrc + (long long)(KT) * 32, &lds[(BUF) * 16384 + t * 8]); \
        gld16(Asrc + (long long)(KT) * 32 + off128, &lds[(BUF) * 16384 + 4096 + t * 8]); } while (0)
#define STAGE_B(BUF, KT) do { \
        gld16(Bsrc + (long long)(KT) * 32, &lds[(BUF) * 16384 + 8192 + t * 8]); \
        gld16(Bsrc + (long long)(KT) * 32 + off128, &lds[(BUF) * 16384 + 12288 + t * 8]); } while (0)

    // swizzled LDS read of one 16x32 fragment
#define RD_A(BUF, M) (*(const bf16x8*)&lds[(BUF) * 16384 + \
        (((wm * 128 + (M) * 16 + frow) * 32 + fq * 8) ^ ((((wm * 128 + (M) * 16 + frow) >> 1) & 3) << 3))])
#define RD_B(BUF, Nn) (*(const bf16x8*)&lds[(BUF) * 16384 + 8192 + \
        (((wn * 64 + (Nn) * 16 + frow) * 32 + fq * 8) ^ ((((wn * 64 + (Nn) * 16 + frow) >> 1) & 3) << 3))])

    // prologue: stage kt=0 and kt=1; wait for kt=0 (leave kt=1's 4 loads in flight)
    STAGE_A(0, 0); STAGE_B(0, 0);
    STAGE_A(1, 1); STAGE_B(1, 1);
    asm volatile("s_waitcnt vmcnt(4)\ns_barrier" ::: "memory");

    for (int kt = 0; kt < NT; ++kt) {
        const int b = kt % 3;
        const int w = (kt + 2) % 3;
        const bool st = (kt + 2) < NT;

        // ---- phase A: quadrant m0-3 x n0-3 ----
        bf16x8 av[4], bv[4];
#pragma unroll
        for (int m = 0; m < 4; ++m) av[m] = RD_A(b, m);
#pragma unroll
        for (int n = 0; n < 4; ++n) bv[n] = RD_B(b, n);
        if (st) STAGE_A(w, kt + 2);
        asm volatile("s_barrier" ::: "memory");
        __builtin_amdgcn_s_setprio(1);
#pragma unroll
        for (int m = 0; m < 4; ++m)
#pragma unroll
            for (int n = 0; n < 4; ++n)
                acc[m][n] = __builtin_amdgcn_mfma_f32_16x16x32_bf16(av[m], bv[n], acc[m][n], 0, 0, 0);
        __builtin_amdgcn_s_setprio(0);
        asm volatile("s_barrier" ::: "memory");

        // ---- phase B: quadrant m4-7 x n0-3 ----
#pragma unroll
        for (int m = 0; m < 4; ++m) av[m] = RD_A(b, 4 + m);
        if (st) STAGE_B(w, kt + 2);
        if (kt + 1 < NT) {
            if (st) asm volatile("s_waitcnt vmcnt(4)\ns_barrier" ::: "memory");
            else    asm volatile("s_waitcnt vmcnt(0)\ns_barrier" ::: "memory");
        } else {
            asm volatile("s_barrier" ::: "memory");
        }
        __builtin_amdgcn_s_setprio(1);
#pragma unroll
        for (int m = 0; m < 4; ++m)
#pragma unroll
            for (int n = 0; n < 4; ++n)
                acc[4 + m][n] = __builtin_amdgcn_mfma_f32_16x16x32_bf16(av[m], bv[n], acc[4 + m][n], 0, 0, 0);
        __builtin_amdgcn_s_setprio(0);
        asm volatile("s_barrier" ::: "memory");
    }
#undef STAGE_A
#undef STAGE_B
#undef RD_A
#undef RD_B

    // epilogue
    const int crow = (lane >> 4) * 4;
    const int ccol = lane & 15;
    const long long cz = (long long)blockIdx.z * sC;
#pragma unroll
    for (int m = 0; m < 8; ++m)
#pragma unroll
        for (int n = 0; n < 4; ++n)
#pragma unroll
            for (int i = 0; i < 4; ++i) {
                long long r = row0 + wm * 128 + m * 16 + crow + i;
                long long c = col0 + wn * 64 + n * 16 + ccol;
                float v = acc[m][n][i] * scale;
                if (BIASMODE == 1) v += bias[c];
                if (DORELU) v = fmaxf(v, 0.0f);
                long long idx = cz + r * (long long)N + c;
                if (OUTBF) ((short*)Cg)[idx] = f2bf(v);
                else ((float*)Cg)[idx] = v;
            }
}

// ---------------------------------------------------------------------------
// NT GEMM: 128x128 tile (round-1, verified) for the small-N matmuls
// ---------------------------------------------------------------------------
template<int OUTBF, int BIASMODE /*0 none,1 col,2 row*/, int DORELU>
__global__ __launch_bounds__(256) void gemm_nt(
    const short* __restrict__ Ag, const short* __restrict__ Bg,
    void* __restrict__ Cg, const float* __restrict__ bias,
    int K, int N, long long sA, long long sB, long long sC, float scale)
{
    __shared__ short lA[128 * 32];
    __shared__ short lB[128 * 32];
    const int t = threadIdx.x;
    const int lane = t & 63;
    const int wave = t >> 6;
    const int wr = (wave >> 1) * 64;
    const int wc = (wave & 1) * 64;
    const long long row0 = (long long)blockIdx.y * 128;
    const long long col0 = (long long)blockIdx.x * 128;
    const short* Ab = Ag + (long long)blockIdx.z * sA + (row0 + (t >> 2)) * (long long)K + (t & 3) * 8;
    const short* Bb = Bg + (long long)blockIdx.z * sB + (col0 + (t >> 2)) * (long long)K + (t & 3) * 8;
    const int frow = lane & 15;
    const int fk = (lane >> 4) * 8;

    f32x4 acc[4][4] = {};
    for (int k0 = 0; k0 < K; k0 += 32) {
        if (k0) __syncthreads();
        gld16(Ab + k0, &lA[t * 8]);
        gld16(Ab + 64LL * K + k0, &lA[2048 + t * 8]);
        gld16(Bb + k0, &lB[t * 8]);
        gld16(Bb + 64LL * K + k0, &lB[2048 + t * 8]);
        __syncthreads();
        bf16x8 af[4], bb[4];
#pragma unroll
        for (int m = 0; m < 4; ++m)
            af[m] = *(const bf16x8*)&lA[(wr + m * 16 + frow) * 32 + fk];
#pragma unroll
        for (int n = 0; n < 4; ++n)
            bb[n] = *(const bf16x8*)&lB[(wc + n * 16 + frow) * 32 + fk];
#pragma unroll
        for (int m = 0; m < 4; ++m)
#pragma unroll
            for (int n = 0; n < 4; ++n)
                acc[m][n] = __builtin_amdgcn_mfma_f32_16x16x32_bf16(af[m], bb[n], acc[m][n], 0, 0, 0);
    }

    const int crow = (lane >> 4) * 4;
    const int ccol = lane & 15;
    const long long cz = (long long)blockIdx.z * sC;
#pragma unroll
    for (int m = 0; m < 4; ++m)
#pragma unroll
        for (int n = 0; n < 4; ++n)
#pragma unroll
            for (int i = 0; i < 4; ++i) {
                long long r = row0 + wr + m * 16 + crow + i;
                long long c = col0 + wc + n * 16 + ccol;
                float v = acc[m][n][i] * scale;
                if (BIASMODE == 1) v += bias[c];
                if (BIASMODE == 2) v += bias[r];
                if (DORELU) v = fmaxf(v, 0.0f);
                long long idx = cz + r * (long long)N + c;
                if (OUTBF) ((short*)Cg)[idx] = f2bf(v);
                else ((float*)Cg)[idx] = v;
            }
}

// fp32 -> bf16 straight cast
__global__ __launch_bounds__(256) void cast_kernel(
    const float* __restrict__ in, short* __restrict__ out, long long n)
{
    long long i = ((long long)blockIdx.x * 256 + threadIdx.x) * 4;
    if (i + 3 < n) {
        float4 v = *(const float4*)&in[i];
        short4 o;
        o.x = f2bf(v.x); o.y = f2bf(v.y); o.z = f2bf(v.z); o.w = f2bf(v.w);
        *(short4*)&out[i] = o;
    }
}

// fp32 [R,C] -> bf16 [C,R], per-batch strides. 64x64 LDS tile.
__global__ __launch_bounds__(256) void transpose_cast(
    const float* __restrict__ in, short* __restrict__ out,
    int R, int C, long long sIn, long long sOut)
{
    __shared__ float tile[64][65];
    const long long zi = (long long)blockIdx.z * sIn;
    const long long zo = (long long)blockIdx.z * sOut;
    const int r0 = blockIdx.y * 64, c0 = blockIdx.x * 64;
    const int lr = threadIdx.x >> 6, lc = threadIdx.x & 63;
#pragma unroll
    for (int i = 0; i < 16; ++i) {
        int r = lr * 16 + i;
        tile[r][lc] = in[zi + (long long)(r0 + r) * C + c0 + lc];
    }
    __syncthreads();
#pragma unroll
    for (int i = 0; i < 16; ++i) {
        int r = lr * 16 + i;
        out[zo + (long long)(c0 + r) * R + r0 + lc] = f2bf(tile[lc][r]);
    }
}

// blended dual softmax over rows of length 2048
__global__ __launch_bounds__(256) void softmax_blend(
    const short* __restrict__ attb, const short* __restrict__ mixb,
    const float* __restrict__ a1p,
    float* __restrict__ outF, short* __restrict__ outB)
{
    const int S = 2048;
    const long long row = blockIdx.x;
    const short* ar = attb + row * S;
    const short* mr = mixb + row * S;
    const int t = threadIdx.x;
    const int wave = t >> 6;

    bf16x8 a8 = *(const bf16x8*)&ar[t * 8];
    bf16x8 m8 = *(const bf16x8*)&mr[t * 8];
    float av[8], mv[8];
#pragma unroll
    for (int i = 0; i < 8; ++i) { av[i] = bf2f(a8[i]); mv[i] = bf2f(m8[i]); }

    float amax = av[0], mmax = mv[0];
#pragma unroll
    for (int i = 1; i < 8; ++i) { amax = fmaxf(amax, av[i]); mmax = fmaxf(mmax, mv[i]); }
#pragma unroll
    for (int o = 32; o; o >>= 1) {
        amax = fmaxf(amax, __shfl_xor(amax, o));
        mmax = fmaxf(mmax, __shfl_xor(mmax, o));
    }
    __shared__ float red[2][4];
    if ((t & 63) == 0) { red[0][wave] = amax; red[1][wave] = mmax; }
    __syncthreads();
    amax = fmaxf(fmaxf(red[0][0], red[0][1]), fmaxf(red[0][2], red[0][3]));
    mmax = fmaxf(fmaxf(red[1][0], red[1][1]), fmaxf(red[1][2], red[1][3]));

    float asum = 0.f, msum = 0.f;
#pragma unroll
    for (int i = 0; i < 8; ++i) {
        av[i] = __expf(av[i] - amax); asum += av[i];
        mv[i] = __expf(mv[i] - mmax); msum += mv[i];
    }
#pragma unroll
    for (int o = 32; o; o >>= 1) {
        asum += __shfl_xor(asum, o);
        msum += __shfl_xor(msum, o);
    }
    __shared__ float red2[2][4];
    if ((t & 63) == 0) { red2[0][wave] = asum; red2[1][wave] = msum; }
    __syncthreads();
    asum = red2[0][0] + red2[0][1] + red2[0][2] + red2[0][3];
    msum = red2[1][0] + red2[1][1] + red2[1][2] + red2[1][3];

    const float a1 = a1p[0];
    const float wm = a1 / msum;
    const float wa = (1.0f - a1) / asum;

    float o0[8];
    bf16x8 ob;
#pragma unroll
    for (int i = 0; i < 8; ++i) {
        float s = wm * mv[i] + wa * av[i];
        o0[i] = s;
        ob[i] = f2bf(s);
    }
    float4 f0, f1;
    f0.x = o0[0]; f0.y = o0[1]; f0.z = o0[2]; f0.w = o0[3];
    f1.x = o0[4]; f1.y = o0[5]; f1.z = o0[6]; f1.w = o0[7];
    *(float4*)&outF[row * S + t * 8] = f0;
    *(float4*)&outF[row * S + t * 8 + 4] = f1;
    *(bf16x8*)&outB[row * S + t * 8] = ob;
}

// LayerNorm over D=384 of (X + Yr); one wave per row, 4 rows/block
template<int WRITE_BF>
__global__ __launch_bounds__(256) void ln_kernel(
    const float* __restrict__ X, const float* __restrict__ Yr,
    const float* __restrict__ g, const float* __restrict__ be,
    float* __restrict__ outF, short* __restrict__ outB)
{
    const int Dm = 384;
    const int wave = threadIdx.x >> 6, lane = threadIdx.x & 63;
    const long long row = (long long)blockIdx.x * 4 + wave;
    const float* x = X + row * Dm;
    const float* y = Yr + row * Dm;
    float h[6];
    float s = 0.f, s2 = 0.f;
#pragma unroll
    for (int j = 0; j < 6; ++j) {
        int c = j * 64 + lane;
        h[j] = x[c] + y[c];
        s += h[j]; s2 += h[j] * h[j];
    }
#pragma unroll
    for (int o = 32; o; o >>= 1) { s += __shfl_xor(s, o); s2 += __shfl_xor(s2, o); }
    const float mean = s * (1.0f / 384.0f);
    const float var = s2 * (1.0f / 384.0f) - mean * mean;
    const float rstd = rsqrtf(var + 1e-5f);
#pragma unroll
    for (int j = 0; j < 6; ++j) {
        int c = j * 64 + lane;
        float v = (h[j] - mean) * rstd * g[c] + be[c];
        outF[row * Dm + c] = v;
        if (WRITE_BF) outB[row * Dm + c] = f2bf(v);
    }
}

extern "C" void kernel_launch(void* const* d_in, const int* in_sizes, int n_in,
                              void* d_out, int out_size, void* d_ws, size_t ws_size,
                              hipStream_t stream) {
    const float* tgt     = (const float*)d_in[0];
    const float* memory  = (const float*)d_in[1];
    const float* a1      = (const float*)d_in[2];
    const float* score_c = (const float*)d_in[3];
    const float* out_c   = (const float*)d_in[4];
    const float* Wq = (const float*)d_in[5];  const float* bq = (const float*)d_in[6];
    const float* Wk = (const float*)d_in[7];  const float* bk = (const float*)d_in[8];
    const float* Wv = (const float*)d_in[9];  const float* bv = (const float*)d_in[10];
    const float* Wu = (const float*)d_in[11]; const float* bu = (const float*)d_in[12];
    const float* Wn = (const float*)d_in[13]; const float* bn = (const float*)d_in[14];
    const float* W1 = (const float*)d_in[15]; const float* b1 = (const float*)d_in[16];
    const float* W2 = (const float*)d_in[17]; const float* b2 = (const float*)d_in[18];
    const float* g1 = (const float*)d_in[19]; const float* be1 = (const float*)d_in[20];
    const float* g2 = (const float*)d_in[21]; const float* be2 = (const float*)d_in[22];

    const long long BT = 16384;            // B*T
    const long long S2 = 2048LL * 2048;    // per-batch score matrix elems
    char* ws = (char*)d_ws;
    size_t off = 0;
    auto A_ = [&](size_t b) { size_t r = off; off += (b + 255) & ~(size_t)255; return r; };

    const size_t oTgtB = A_(BT * 384 * 2);
    const size_t oMemB = A_(BT * 256 * 2);
    const size_t oOutcB = A_(BT * 384 * 2);
    const size_t oWqT = A_(384 * 384 * 2);
    const size_t oWuT = A_(384 * 384 * 2);
    const size_t oWnT = A_(384 * 384 * 2);
    const size_t oWkT = A_(384 * 256 * 2);
    const size_t oWvT = A_(384 * 256 * 2);
    const size_t oW1T = A_(1536 * 384 * 2);
    const size_t oW2T = A_(384 * 1536 * 2);
    const size_t oQ   = A_(BT * 384 * 2);
    const size_t oK   = A_(BT * 384 * 2);
    const size_t oVT  = A_(8LL * 384 * 2048 * 2);
    const size_t oUnk = A_(BT * 384 * 2);
    const size_t oKno = A_(BT * 384 * 2);
    const size_t oJ   = A_(8 * S2 * 2);   // score1_bf, later score_bf
    const size_t oKr  = A_(8 * S2 * 2);   // score_c^T bf16, later z fp32
    const size_t oL   = A_(8 * S2 * 2);   // att_bf, later h_bf
    const size_t oM   = A_(8 * S2 * 2);   // mixed_bf, later ff fp32
    const size_t oX   = A_(BT * 384 * 4);
    const size_t oXB  = A_(BT * 384 * 2);

    short* tgt_bf  = (short*)(ws + oTgtB);
    short* mem_bf  = (short*)(ws + oMemB);
    short* outc_bf = (short*)(ws + oOutcB);
    short* WqT = (short*)(ws + oWqT);
    short* WuT = (short*)(ws + oWuT);
    short* WnT = (short*)(ws + oWnT);
    short* WkT = (short*)(ws + oWkT);
    short* WvT = (short*)(ws + oWvT);
    short* W1T = (short*)(ws + oW1T);
    short* W2T = (short*)(ws + oW2T);
    short* q_bf  = (short*)(ws + oQ);
    short* k_bf  = (short*)(ws + oK);
    short* vT_bf = (short*)(ws + oVT);
    short* unk_bf = (short*)(ws + oUnk);
    short* kno_bf = (short*)(ws + oKno);
    short* sc1_bf = (short*)(ws + oJ);
    short* score_bf = (short*)(ws + oJ);     // alias (score1 dead after mixed)
    short* scoreCt = (short*)(ws + oKr);
    float* z_f = (float*)(ws + oKr);         // alias (score_c^T dead after mixed)
    short* att_bf = (short*)(ws + oL);
    short* h_bf = (short*)(ws + oL);         // alias (att dead after blend)
    short* mix_bf = (short*)(ws + oM);
    float* ff_f = (float*)(ws + oM);         // alias (mixed dead after blend)
    float* x_f = (float*)(ws + oX);
    short* x_bf = (short*)(ws + oXB);

    float* outMain = (float*)d_out;
    float* outScore = (float*)d_out + 6291456;   // B*T*D elements

    const float SC = 0.05103103630798288f;  // 1/sqrt(384)
    dim3 blk(256);
    dim3 blk512(512);

    // casts
    cast_kernel<<<6144, blk, 0, stream>>>(tgt, tgt_bf, BT * 384);
    cast_kernel<<<4096, blk, 0, stream>>>(memory, mem_bf, BT * 256);
    cast_kernel<<<6144, blk, 0, stream>>>(out_c, outc_bf, BT * 384);
    // weight transposes ([K,N] -> [N,K] bf16)
    transpose_cast<<<dim3(6, 6, 1), blk, 0, stream>>>(Wq, WqT, 384, 384, 0, 0);
    transpose_cast<<<dim3(6, 4, 1), blk, 0, stream>>>(Wk, WkT, 256, 384, 0, 0);
    transpose_cast<<<dim3(6, 4, 1), blk, 0, stream>>>(Wv, WvT, 256, 384, 0, 0);
    transpose_cast<<<dim3(6, 6, 1), blk, 0, stream>>>(Wu, WuT, 384, 384, 0, 0);
    transpose_cast<<<dim3(6, 6, 1), blk, 0, stream>>>(Wn, WnT, 384, 384, 0, 0);
    transpose_cast<<<dim3(24, 6, 1), blk, 0, stream>>>(W1, W1T, 384, 1536, 0, 0);
    transpose_cast<<<dim3(6, 24, 1), blk, 0, stream>>>(W2, W2T, 1536, 384, 0, 0);
    // score_c^T per batch
    transpose_cast<<<dim3(32, 32, 8), blk, 0, stream>>>(score_c, scoreCt, 2048, 2048, S2, S2);

    // projections (bf16 out)
    gemm_nt<1, 1, 0><<<dim3(3, 128, 1), blk, 0, stream>>>(tgt_bf, WqT, q_bf, bq, 384, 384, 0, 0, 0, 1.0f);
    gemm_nt<1, 1, 0><<<dim3(3, 128, 1), blk, 0, stream>>>(mem_bf, WkT, k_bf, bk, 256, 384, 0, 0, 0, 1.0f);
    gemm_nt<1, 2, 0><<<dim3(16, 3, 8), blk, 0, stream>>>(WvT, mem_bf, vT_bf, bv, 256, 2048,
                                                         0, 2048LL * 256, 384LL * 2048, 1.0f);
    gemm_nt<1, 1, 0><<<dim3(3, 128, 1), blk, 0, stream>>>(tgt_bf, WuT, unk_bf, bu, 384, 384, 0, 0, 0, 1.0f);
    gemm_nt<1, 1, 0><<<dim3(3, 128, 1), blk, 0, stream>>>(outc_bf, WnT, kno_bf, bn, 384, 384, 0, 0, 0, 1.0f);

    // att = scale * q k^T ; score1 = scale * unknow know^T  (256^2 pipelined kernel)
    gemm256<1, 0, 0><<<dim3(8, 8, 8), blk512, 0, stream>>>(q_bf, k_bf, att_bf, nullptr, 384, 2048,
                                                           2048LL * 384, 2048LL * 384, S2, SC);
    gemm256<1, 0, 0><<<dim3(8, 8, 8), blk512, 0, stream>>>(unk_bf, kno_bf, sc1_bf, nullptr, 384, 2048,
                                                           2048LL * 384, 2048LL * 384, S2, SC);
    // mixed = score1 @ score_c
    gemm256<1, 0, 0><<<dim3(8, 8, 8), blk512, 0, stream>>>(sc1_bf, scoreCt, mix_bf, nullptr, 2048, 2048,
                                                           S2, S2, S2, 1.0f);
    // score = a1*softmax(mixed) + (1-a1)*softmax(att)
    softmax_blend<<<16384, blk, 0, stream>>>(att_bf, mix_bf, a1, outScore, score_bf);
    // z = score @ v
    gemm_nt<0, 0, 0><<<dim3(3, 16, 8), blk, 0, stream>>>(score_bf, vT_bf, z_f, nullptr, 2048, 384,
                                                         S2, 384LL * 2048, 2048LL * 384, 1.0f);
    // x = LN(tgt + z)
    ln_kernel<1><<<4096, blk, 0, stream>>>(tgt, z_f, g1, be1, x_f, x_bf);
    // FFN
    gemm256<1, 1, 1><<<dim3(6, 64, 1), blk512, 0, stream>>>(x_bf, W1T, h_bf, b1, 384, 1536, 0, 0, 0, 1.0f);
    gemm_nt<0, 1, 0><<<dim3(3, 128, 1), blk, 0, stream>>>(h_bf, W2T, ff_f, b2, 1536, 384, 0, 0, 0, 1.0f);
    // out = LN(x + ff)
    ln_kernel<0><<<4096, blk, 0, stream>>>(x_f, ff_f, g2, be2, outMain, nullptr);
}

// Round 3
// 595.957 us; speedup vs baseline: 1.1231x; 1.0551x over previous
//
#include <hip/hip_runtime.h>
#include <stdint.h>

typedef __attribute__((ext_vector_type(8))) short bf16x8;
typedef __attribute__((ext_vector_type(4))) float f32x4;

__device__ __forceinline__ short f2bf(float f) {
    union { float f; unsigned u; } v; v.f = f;
    unsigned r = v.u + 0x7fffu + ((v.u >> 16) & 1u);
    return (short)(r >> 16);
}
__device__ __forceinline__ float bf2f(short s) {
    union { unsigned u; float f; } v;
    v.u = ((unsigned)(unsigned short)s) << 16;
    return v.f;
}

__device__ __forceinline__ void gld16(const void* g, void* l) {
    auto gp = reinterpret_cast<const __attribute__((address_space(1))) unsigned int*>(
        reinterpret_cast<uintptr_t>(g));
    auto lp = reinterpret_cast<__attribute__((address_space(3))) unsigned int*>(
        reinterpret_cast<uintptr_t>(l));
    __builtin_amdgcn_global_load_lds(gp, lp, 16, 0, 0);
}

// ---------------------------------------------------------------------------
// gemm256p: 256x256 NT GEMM, BK=64, 8 waves (2Mx4N), 2x64KB LDS dbuf split in
// 4 slots/K-tile (A_k0|B_k0|A_k1|B_k1). 4 phases/K-tile, each:
//   {ds_read subtile || stage 1 slot of kt+1} -> barrier -> setprio(1) ->
//   16 MFMA -> setprio(0) -> [counted vmcnt at 2-phase boundaries] -> barrier
// Counted waits: vmcnt(4) (per-wave: 2 loads/slot, 4 slots in flight; oldest
// 4 must retire, newest 4 stay in flight). Never drains in steady state.
// 2-way (free) XOR bank swizzle, src-preswizzled. XCD-bijective block swizzle.
// Requires M%256==0, N%256==0, K%64==0, nwg%8==0.
// ---------------------------------------------------------------------------
template<int OUTBF, int BIASMODE /*0 none,1 col*/, int DORELU>
__global__ __launch_bounds__(512, 2) void gemm256p(
    const short* __restrict__ Ag, const short* __restrict__ Bg,
    void* __restrict__ Cg, const float* __restrict__ bias,
    int K, int N, long long sA, long long sB, long long sC, float scale)
{
    __shared__ short lds[2 * 32768];   // 128 KiB
    const int t = threadIdx.x;
    const int lane = t & 63;
    const int wid = t >> 6;
    const int wm = wid >> 2, wn = wid & 3;

    // XCD-aware bijective swizzle (nwg % 8 == 0 guaranteed by launch config)
    const int gx = gridDim.x, gy = gridDim.y;
    const int nwg = gx * gy * gridDim.z;
    int id = blockIdx.x + gx * (blockIdx.y + gy * blockIdx.z);
    id = (id & 7) * (nwg >> 3) + (id >> 3);
    const int bx = id % gx;
    const int by = (id / gx) % gy;
    const int bz = id / (gx * gy);

    const long long row0 = (long long)by * 256;
    const long long col0 = (long long)bx * 256;
    const int NT = K >> 6;

    const int srow = t >> 2;
    const int gk = ((t & 3) ^ ((srow >> 1) & 3)) * 8;
    const short* Asrc = Ag + (long long)bz * sA + (row0 + srow) * (long long)K + gk;
    const short* Bsrc = Bg + (long long)bz * sB + (col0 + srow) * (long long)K + gk;
    const long long o128 = 128LL * (long long)K;

    const int frow = lane & 15;
    const int fcol = ((lane >> 4) * 8) ^ (((frow >> 1) & 3) << 3);  // swizzled col (shorts)

    f32x4 acc[8][4] = {};

#define SLOT_STAGE(SB, SRC) do { \
        gld16((SRC), &lds[(SB) + t * 8]); \
        gld16((SRC) + o128, &lds[(SB) + 4096 + t * 8]); } while (0)

    // prologue: stage all 4 slots of kt=0; need first two done -> vmcnt(4)
    SLOT_STAGE(0,     Asrc);
    SLOT_STAGE(8192,  Bsrc);
    SLOT_STAGE(16384, Asrc + 32);
    SLOT_STAGE(24576, Bsrc + 32);
    asm volatile("s_waitcnt vmcnt(4)\ns_barrier" ::: "memory");

    for (int kt = 0; kt < NT; ++kt) {
        const int rb = (kt & 1) << 15;
        const int wb = ((kt + 1) & 1) << 15;
        const bool st = (kt + 1) < NT;
        const long long kc = (long long)(kt + 1) << 6;

        bf16x8 a0[4], a1[4], b0[4], b1[4];

        // ---- ph0: read A_k0 m0-3 + B_k0 n0-3; stage A_k0(kt+1) ----
#pragma unroll
        for (int m = 0; m < 4; ++m)
            a0[m] = *(const bf16x8*)&lds[rb + (wm * 128 + m * 16 + frow) * 32 + fcol];
#pragma unroll
        for (int n = 0; n < 4; ++n)
            b0[n] = *(const bf16x8*)&lds[rb + 8192 + (wn * 64 + n * 16 + frow) * 32 + fcol];
        if (st) SLOT_STAGE(wb, Asrc + kc);
        asm volatile("s_barrier" ::: "memory");
        __builtin_amdgcn_s_setprio(1);
#pragma unroll
        for (int m = 0; m < 4; ++m)
#pragma unroll
            for (int n = 0; n < 4; ++n)
                acc[m][n] = __builtin_amdgcn_mfma_f32_16x16x32_bf16(a0[m], b0[n], acc[m][n], 0, 0, 0);
        __builtin_amdgcn_s_setprio(0);
        asm volatile("s_barrier" ::: "memory");

        // ---- ph1: read A_k0 m4-7; stage B_k0(kt+1) ----
#pragma unroll
        for (int m = 0; m < 4; ++m)
            a1[m] = *(const bf16x8*)&lds[rb + (wm * 128 + 64 + m * 16 + frow) * 32 + fcol];
        if (st) SLOT_STAGE(wb + 8192, Bsrc + kc);
        asm volatile("s_barrier" ::: "memory");
        __builtin_amdgcn_s_setprio(1);
#pragma unroll
        for (int m = 0; m < 4; ++m)
#pragma unroll
            for (int n = 0; n < 4; ++n)
                acc[4 + m][n] = __builtin_amdgcn_mfma_f32_16x16x32_bf16(a1[m], b0[n], acc[4 + m][n], 0, 0, 0);
        __builtin_amdgcn_s_setprio(0);
        // boundary: need A_k1,B_k1(kt) done (oldest); newest 4 = k0 slots of kt+1
        if (st) asm volatile("s_waitcnt vmcnt(4)\ns_barrier" ::: "memory");
        else    asm volatile("s_waitcnt vmcnt(0)\ns_barrier" ::: "memory");

        // ---- ph2: read A_k1 m0-3 + B_k1 n0-3; stage A_k1(kt+1) ----
#pragma unroll
        for (int m = 0; m < 4; ++m)
            a0[m] = *(const bf16x8*)&lds[rb + 16384 + (wm * 128 + m * 16 + frow) * 32 + fcol];
#pragma unroll
        for (int n = 0; n < 4; ++n)
            b1[n] = *(const bf16x8*)&lds[rb + 24576 + (wn * 64 + n * 16 + frow) * 32 + fcol];
        if (st) SLOT_STAGE(wb + 16384, Asrc + kc + 32);
        asm volatile("s_barrier" ::: "memory");
        __builtin_amdgcn_s_setprio(1);
#pragma unroll
        for (int m = 0; m < 4; ++m)
#pragma unroll
            for (int n = 0; n < 4; ++n)
                acc[m][n] = __builtin_amdgcn_mfma_f32_16x16x32_bf16(a0[m], b1[n], acc[m][n], 0, 0, 0);
        __builtin_amdgcn_s_setprio(0);
        asm volatile("s_barrier" ::: "memory");

        // ---- ph3: read A_k1 m4-7; stage B_k1(kt+1) ----
#pragma unroll
        for (int m = 0; m < 4; ++m)
            a1[m] = *(const bf16x8*)&lds[rb + 16384 + (wm * 128 + 64 + m * 16 + frow) * 32 + fcol];
        if (st) SLOT_STAGE(wb + 24576, Bsrc + kc + 32);
        asm volatile("s_barrier" ::: "memory");
        __builtin_amdgcn_s_setprio(1);
#pragma unroll
        for (int m = 0; m < 4; ++m)
#pragma unroll
            for (int n = 0; n < 4; ++n)
                acc[4 + m][n] = __builtin_amdgcn_mfma_f32_16x16x32_bf16(a1[m], b1[n], acc[4 + m][n], 0, 0, 0);
        __builtin_amdgcn_s_setprio(0);
        // boundary: need A_k0,B_k0(kt+1) done; newest 4 = k1 slots of kt+1
        if (st) asm volatile("s_waitcnt vmcnt(4)\ns_barrier" ::: "memory");
        else    asm volatile("s_barrier" ::: "memory");
    }
#undef SLOT_STAGE

    // epilogue
    const int crow = (lane >> 4) * 4;
    const int ccol = lane & 15;
    const long long cz = (long long)bz * sC;
#pragma unroll
    for (int m = 0; m < 8; ++m)
#pragma unroll
        for (int n = 0; n < 4; ++n)
#pragma unroll
            for (int i = 0; i < 4; ++i) {
                long long r = row0 + wm * 128 + m * 16 + crow + i;
                long long c = col0 + wn * 64 + n * 16 + ccol;
                float v = acc[m][n][i] * scale;
                if (BIASMODE == 1) v += bias[c];
                if (DORELU) v = fmaxf(v, 0.0f);
                long long idx = cz + r * (long long)N + c;
                if (OUTBF) ((short*)Cg)[idx] = f2bf(v);
                else ((float*)Cg)[idx] = v;
            }
}

// ---------------------------------------------------------------------------
// NT GEMM: 128x128 tile (round-1, verified) for the small-N matmuls
// ---------------------------------------------------------------------------
template<int OUTBF, int BIASMODE /*0 none,1 col,2 row*/, int DORELU>
__global__ __launch_bounds__(256) void gemm_nt(
    const short* __restrict__ Ag, const short* __restrict__ Bg,
    void* __restrict__ Cg, const float* __restrict__ bias,
    int K, int N, long long sA, long long sB, long long sC, float scale)
{
    __shared__ short lA[128 * 32];
    __shared__ short lB[128 * 32];
    const int t = threadIdx.x;
    const int lane = t & 63;
    const int wave = t >> 6;
    const int wr = (wave >> 1) * 64;
    const int wc = (wave & 1) * 64;
    const long long row0 = (long long)blockIdx.y * 128;
    const long long col0 = (long long)blockIdx.x * 128;
    const short* Ab = Ag + (long long)blockIdx.z * sA + (row0 + (t >> 2)) * (long long)K + (t & 3) * 8;
    const short* Bb = Bg + (long long)blockIdx.z * sB + (col0 + (t >> 2)) * (long long)K + (t & 3) * 8;
    const int frow = lane & 15;
    const int fk = (lane >> 4) * 8;

    f32x4 acc[4][4] = {};
    for (int k0 = 0; k0 < K; k0 += 32) {
        if (k0) __syncthreads();
        gld16(Ab + k0, &lA[t * 8]);
        gld16(Ab + 64LL * K + k0, &lA[2048 + t * 8]);
        gld16(Bb + k0, &lB[t * 8]);
        gld16(Bb + 64LL * K + k0, &lB[2048 + t * 8]);
        __syncthreads();
        bf16x8 af[4], bb[4];
#pragma unroll
        for (int m = 0; m < 4; ++m)
            af[m] = *(const bf16x8*)&lA[(wr + m * 16 + frow) * 32 + fk];
#pragma unroll
        for (int n = 0; n < 4; ++n)
            bb[n] = *(const bf16x8*)&lB[(wc + n * 16 + frow) * 32 + fk];
#pragma unroll
        for (int m = 0; m < 4; ++m)
#pragma unroll
            for (int n = 0; n < 4; ++n)
                acc[m][n] = __builtin_amdgcn_mfma_f32_16x16x32_bf16(af[m], bb[n], acc[m][n], 0, 0, 0);
    }

    const int crow = (lane >> 4) * 4;
    const int ccol = lane & 15;
    const long long cz = (long long)blockIdx.z * sC;
#pragma unroll
    for (int m = 0; m < 4; ++m)
#pragma unroll
        for (int n = 0; n < 4; ++n)
#pragma unroll
            for (int i = 0; i < 4; ++i) {
                long long r = row0 + wr + m * 16 + crow + i;
                long long c = col0 + wc + n * 16 + ccol;
                float v = acc[m][n][i] * scale;
                if (BIASMODE == 1) v += bias[c];
                if (BIASMODE == 2) v += bias[r];
                if (DORELU) v = fmaxf(v, 0.0f);
                long long idx = cz + r * (long long)N + c;
                if (OUTBF) ((short*)Cg)[idx] = f2bf(v);
                else ((float*)Cg)[idx] = v;
            }
}

// fp32 -> bf16 straight cast
__global__ __launch_bounds__(256) void cast_kernel(
    const float* __restrict__ in, short* __restrict__ out, long long n)
{
    long long i = ((long long)blockIdx.x * 256 + threadIdx.x) * 4;
    if (i + 3 < n) {
        float4 v = *(const float4*)&in[i];
        short4 o;
        o.x = f2bf(v.x); o.y = f2bf(v.y); o.z = f2bf(v.z); o.w = f2bf(v.w);
        *(short4*)&out[i] = o;
    }
}

// fp32 [R,C] -> bf16 [C,R], per-batch strides. 64x64 LDS tile.
__global__ __launch_bounds__(256) void transpose_cast(
    const float* __restrict__ in, short* __restrict__ out,
    int R, int C, long long sIn, long long sOut)
{
    __shared__ float tile[64][65];
    const long long zi = (long long)blockIdx.z * sIn;
    const long long zo = (long long)blockIdx.z * sOut;
    const int r0 = blockIdx.y * 64, c0 = blockIdx.x * 64;
    const int lr = threadIdx.x >> 6, lc = threadIdx.x & 63;
#pragma unroll
    for (int i = 0; i < 16; ++i) {
        int r = lr * 16 + i;
        tile[r][lc] = in[zi + (long long)(r0 + r) * C + c0 + lc];
    }
    __syncthreads();
#pragma unroll
    for (int i = 0; i < 16; ++i) {
        int r = lr * 16 + i;
        out[zo + (long long)(c0 + r) * R + r0 + lc] = f2bf(tile[lc][r]);
    }
}

// blended dual softmax over rows of length 2048
__global__ __launch_bounds__(256) void softmax_blend(
    const short* __restrict__ attb, const short* __restrict__ mixb,
    const float* __restrict__ a1p,
    float* __restrict__ outF, short* __restrict__ outB)
{
    const int S = 2048;
    const long long row = blockIdx.x;
    const short* ar = attb + row * S;
    const short* mr = mixb + row * S;
    const int t = threadIdx.x;
    const int wave = t >> 6;

    bf16x8 a8 = *(const bf16x8*)&ar[t * 8];
    bf16x8 m8 = *(const bf16x8*)&mr[t * 8];
    float av[8], mv[8];
#pragma unroll
    for (int i = 0; i < 8; ++i) { av[i] = bf2f(a8[i]); mv[i] = bf2f(m8[i]); }

    float amax = av[0], mmax = mv[0];
#pragma unroll
    for (int i = 1; i < 8; ++i) { amax = fmaxf(amax, av[i]); mmax = fmaxf(mmax, mv[i]); }
#pragma unroll
    for (int o = 32; o; o >>= 1) {
        amax = fmaxf(amax, __shfl_xor(amax, o));
        mmax = fmaxf(mmax, __shfl_xor(mmax, o));
    }
    __shared__ float red[2][4];
    if ((t & 63) == 0) { red[0][wave] = amax; red[1][wave] = mmax; }
    __syncthreads();
    amax = fmaxf(fmaxf(red[0][0], red[0][1]), fmaxf(red[0][2], red[0][3]));
    mmax = fmaxf(fmaxf(red[1][0], red[1][1]), fmaxf(red[1][2], red[1][3]));

    float asum = 0.f, msum = 0.f;
#pragma unroll
    for (int i = 0; i < 8; ++i) {
        av[i] = __expf(av[i] - amax); asum += av[i];
        mv[i] = __expf(mv[i] - mmax); msum += mv[i];
    }
#pragma unroll
    for (int o = 32; o; o >>= 1) {
        asum += __shfl_xor(asum, o);
        msum += __shfl_xor(msum, o);
    }
    __shared__ float red2[2][4];
    if ((t & 63) == 0) { red2[0][wave] = asum; red2[1][wave] = msum; }
    __syncthreads();
    asum = red2[0][0] + red2[0][1] + red2[0][2] + red2[0][3];
    msum = red2[1][0] + red2[1][1] + red2[1][2] + red2[1][3];

    const float a1 = a1p[0];
    const float wm = a1 / msum;
    const float wa = (1.0f - a1) / asum;

    float o0[8];
    bf16x8 ob;
#pragma unroll
    for (int i = 0; i < 8; ++i) {
        float s = wm * mv[i] + wa * av[i];
        o0[i] = s;
        ob[i] = f2bf(s);
    }
    float4 f0, f1;
    f0.x = o0[0]; f0.y = o0[1]; f0.z = o0[2]; f0.w = o0[3];
    f1.x = o0[4]; f1.y = o0[5]; f1.z = o0[6]; f1.w = o0[7];
    *(float4*)&outF[row * S + t * 8] = f0;
    *(float4*)&outF[row * S + t * 8 + 4] = f1;
    *(bf16x8*)&outB[row * S + t * 8] = ob;
}

// LayerNorm over D=384 of (X + Yr); one wave per row, 4 rows/block
template<int WRITE_BF>
__global__ __launch_bounds__(256) void ln_kernel(
    const float* __restrict__ X, const float* __restrict__ Yr,
    const float* __restrict__ g, const float* __restrict__ be,
    float* __restrict__ outF, short* __restrict__ outB)
{
    const int Dm = 384;
    const int wave = threadIdx.x >> 6, lane = threadIdx.x & 63;
    const long long row = (long long)blockIdx.x * 4 + wave;
    const float* x = X + row * Dm;
    const float* y = Yr + row * Dm;
    float h[6];
    float s = 0.f, s2 = 0.f;
#pragma unroll
    for (int j = 0; j < 6; ++j) {
        int c = j * 64 + lane;
        h[j] = x[c] + y[c];
        s += h[j]; s2 += h[j] * h[j];
    }
#pragma unroll
    for (int o = 32; o; o >>= 1) { s += __shfl_xor(s, o); s2 += __shfl_xor(s2, o); }
    const float mean = s * (1.0f / 384.0f);
    const float var = s2 * (1.0f / 384.0f) - mean * mean;
    const float rstd = rsqrtf(var + 1e-5f);
#pragma unroll
    for (int j = 0; j < 6; ++j) {
        int c = j * 64 + lane;
        float v = (h[j] - mean) * rstd * g[c] + be[c];
        outF[row * Dm + c] = v;
        if (WRITE_BF) outB[row * Dm + c] = f2bf(v);
    }
}

extern "C" void kernel_launch(void* const* d_in, const int* in_sizes, int n_in,
                              void* d_out, int out_size, void* d_ws, size_t ws_size,
                              hipStream_t stream) {
    const float* tgt     = (const float*)d_in[0];
    const float* memory  = (const float*)d_in[1];
    const float* a1      = (const float*)d_in[2];
    const float* score_c = (const float*)d_in[3];
    const float* out_c   = (const float*)d_in[4];
    const float* Wq = (const float*)d_in[5];  const float* bq = (const float*)d_in[6];
    const float* Wk = (const float*)d_in[7];  const float* bk = (const float*)d_in[8];
    const float* Wv = (const float*)d_in[9];  const float* bv = (const float*)d_in[10];
    const float* Wu = (const float*)d_in[11]; const float* bu = (const float*)d_in[12];
    const float* Wn = (const float*)d_in[13]; const float* bn = (const float*)d_in[14];
    const float* W1 = (const float*)d_in[15]; const float* b1 = (const float*)d_in[16];
    const float* W2 = (const float*)d_in[17]; const float* b2 = (const float*)d_in[18];
    const float* g1 = (const float*)d_in[19]; const float* be1 = (const float*)d_in[20];
    const float* g2 = (const float*)d_in[21]; const float* be2 = (const float*)d_in[22];

    const long long BT = 16384;            // B*T
    const long long S2 = 2048LL * 2048;    // per-batch score matrix elems
    char* ws = (char*)d_ws;
    size_t off = 0;
    auto A_ = [&](size_t b) { size_t r = off; off += (b + 255) & ~(size_t)255; return r; };

    const size_t oTgtB = A_(BT * 384 * 2);
    const size_t oMemB = A_(BT * 256 * 2);
    const size_t oOutcB = A_(BT * 384 * 2);
    const size_t oWqT = A_(384 * 384 * 2);
    const size_t oWuT = A_(384 * 384 * 2);
    const size_t oWnT = A_(384 * 384 * 2);
    const size_t oWkT = A_(384 * 256 * 2);
    const size_t oWvT = A_(384 * 256 * 2);
    const size_t oW1T = A_(1536 * 384 * 2);
    const size_t oW2T = A_(384 * 1536 * 2);
    const size_t oQ   = A_(BT * 384 * 2);
    const size_t oK   = A_(BT * 384 * 2);
    const size_t oVT  = A_(8LL * 384 * 2048 * 2);
    const size_t oUnk = A_(BT * 384 * 2);
    const size_t oKno = A_(BT * 384 * 2);
    const size_t oJ   = A_(8 * S2 * 2);   // score1_bf, later score_bf
    const size_t oKr  = A_(8 * S2 * 2);   // score_c^T bf16, later z fp32
    const size_t oL   = A_(8 * S2 * 2);   // att_bf, later h_bf
    const size_t oM   = A_(8 * S2 * 2);   // mixed_bf, later ff fp32
    const size_t oX   = A_(BT * 384 * 4);
    const size_t oXB  = A_(BT * 384 * 2);

    short* tgt_bf  = (short*)(ws + oTgtB);
    short* mem_bf  = (short*)(ws + oMemB);
    short* outc_bf = (short*)(ws + oOutcB);
    short* WqT = (short*)(ws + oWqT);
    short* WuT = (short*)(ws + oWuT);
    short* WnT = (short*)(ws + oWnT);
    short* WkT = (short*)(ws + oWkT);
    short* WvT = (short*)(ws + oWvT);
    short* W1T = (short*)(ws + oW1T);
    short* W2T = (short*)(ws + oW2T);
    short* q_bf  = (short*)(ws + oQ);
    short* k_bf  = (short*)(ws + oK);
    short* vT_bf = (short*)(ws + oVT);
    short* unk_bf = (short*)(ws + oUnk);
    short* kno_bf = (short*)(ws + oKno);
    short* sc1_bf = (short*)(ws + oJ);
    short* score_bf = (short*)(ws + oJ);     // alias (score1 dead after mixed)
    short* scoreCt = (short*)(ws + oKr);
    float* z_f = (float*)(ws + oKr);         // alias (score_c^T dead after mixed)
    short* att_bf = (short*)(ws + oL);
    short* h_bf = (short*)(ws + oL);         // alias (att dead after blend)
    short* mix_bf = (short*)(ws + oM);
    float* ff_f = (float*)(ws + oM);         // alias (mixed dead after blend)
    float* x_f = (float*)(ws + oX);
    short* x_bf = (short*)(ws + oXB);

    float* outMain = (float*)d_out;
    float* outScore = (float*)d_out + 6291456;   // B*T*D elements

    const float SC = 0.05103103630798288f;  // 1/sqrt(384)
    dim3 blk(256);
    dim3 blk512(512);

    // casts
    cast_kernel<<<6144, blk, 0, stream>>>(tgt, tgt_bf, BT * 384);
    cast_kernel<<<4096, blk, 0, stream>>>(memory, mem_bf, BT * 256);
    cast_kernel<<<6144, blk, 0, stream>>>(out_c, outc_bf, BT * 384);
    // weight transposes ([K,N] -> [N,K] bf16)
    transpose_cast<<<dim3(6, 6, 1), blk, 0, stream>>>(Wq, WqT, 384, 384, 0, 0);
    transpose_cast<<<dim3(6, 4, 1), blk, 0, stream>>>(Wk, WkT, 256, 384, 0, 0);
    transpose_cast<<<dim3(6, 4, 1), blk, 0, stream>>>(Wv, WvT, 256, 384, 0, 0);
    transpose_cast<<<dim3(6, 6, 1), blk, 0, stream>>>(Wu, WuT, 384, 384, 0, 0);
    transpose_cast<<<dim3(6, 6, 1), blk, 0, stream>>>(Wn, WnT, 384, 384, 0, 0);
    transpose_cast<<<dim3(24, 6, 1), blk, 0, stream>>>(W1, W1T, 384, 1536, 0, 0);
    transpose_cast<<<dim3(6, 24, 1), blk, 0, stream>>>(W2, W2T, 1536, 384, 0, 0);
    // score_c^T per batch
    transpose_cast<<<dim3(32, 32, 8), blk, 0, stream>>>(score_c, scoreCt, 2048, 2048, S2, S2);

    // projections (bf16 out)
    gemm_nt<1, 1, 0><<<dim3(3, 128, 1), blk, 0, stream>>>(tgt_bf, WqT, q_bf, bq, 384, 384, 0, 0, 0, 1.0f);
    gemm_nt<1, 1, 0><<<dim3(3, 128, 1), blk, 0, stream>>>(mem_bf, WkT, k_bf, bk, 256, 384, 0, 0, 0, 1.0f);
    gemm_nt<1, 2, 0><<<dim3(16, 3, 8), blk, 0, stream>>>(WvT, mem_bf, vT_bf, bv, 256, 2048,
                                                         0, 2048LL * 256, 384LL * 2048, 1.0f);
    gemm_nt<1, 1, 0><<<dim3(3, 128, 1), blk, 0, stream>>>(tgt_bf, WuT, unk_bf, bu, 384, 384, 0, 0, 0, 1.0f);
    gemm_nt<1, 1, 0><<<dim3(3, 128, 1), blk, 0, stream>>>(outc_bf, WnT, kno_bf, bn, 384, 384, 0, 0, 0, 1.0f);

    // att = scale * q k^T ; score1 = scale * unknow know^T  (pipelined 256^2)
    gemm256p<1, 0, 0><<<dim3(8, 8, 8), blk512, 0, stream>>>(q_bf, k_bf, att_bf, nullptr, 384, 2048,
                                                            2048LL * 384, 2048LL * 384, S2, SC);
    gemm256p<1, 0, 0><<<dim3(8, 8, 8), blk512, 0, stream>>>(unk_bf, kno_bf, sc1_bf, nullptr, 384, 2048,
                                                            2048LL * 384, 2048LL * 384, S2, SC);
    // mixed = score1 @ score_c
    gemm256p<1, 0, 0><<<dim3(8, 8, 8), blk512, 0, stream>>>(sc1_bf, scoreCt, mix_bf, nullptr, 2048, 2048,
                                                            S2, S2, S2, 1.0f);
    // score = a1*softmax(mixed) + (1-a1)*softmax(att)
    softmax_blend<<<16384, blk, 0, stream>>>(att_bf, mix_bf, a1, outScore, score_bf);
    // z = score @ v
    gemm_nt<0, 0, 0><<<dim3(3, 16, 8), blk, 0, stream>>>(score_bf, vT_bf, z_f, nullptr, 2048, 384,
                                                         S2, 384LL * 2048, 2048LL * 384, 1.0f);
    // x = LN(tgt + z)
    ln_kernel<1><<<4096, blk, 0, stream>>>(tgt, z_f, g1, be1, x_f, x_bf);
    // FFN
    gemm256p<1, 1, 1><<<dim3(6, 64, 1), blk512, 0, stream>>>(x_bf, W1T, h_bf, b1, 384, 1536, 0, 0, 0, 1.0f);
    gemm_nt<0, 1, 0><<<dim3(3, 128, 1), blk, 0, stream>>>(h_bf, W2T, ff_f, b2, 1536, 384, 0, 0, 0, 1.0f);
    // out = LN(x + ff)
    ln_kernel<0><<<4096, blk, 0, stream>>>(x_f, ff_f, g2, be2, outMain, nullptr);
}

// Round 4
// 525.050 us; speedup vs baseline: 1.2747x; 1.1350x over previous
//
#include <hip/hip_runtime.h>
#include <stdint.h>

typedef __attribute__((ext_vector_type(8))) short bf16x8;
typedef __attribute__((ext_vector_type(4))) float f32x4;

__device__ __forceinline__ short f2bf(float f) {
    union { float f; unsigned u; } v; v.f = f;
    unsigned r = v.u + 0x7fffu + ((v.u >> 16) & 1u);
    return (short)(r >> 16);
}
__device__ __forceinline__ float bf2f(short s) {
    union { unsigned u; float f; } v;
    v.u = ((unsigned)(unsigned short)s) << 16;
    return v.f;
}

__device__ __forceinline__ void gld16(const void* g, void* l) {
    auto gp = reinterpret_cast<const __attribute__((address_space(1))) unsigned int*>(
        reinterpret_cast<uintptr_t>(g));
    auto lp = reinterpret_cast<__attribute__((address_space(3))) unsigned int*>(
        reinterpret_cast<uintptr_t>(l));
    __builtin_amdgcn_global_load_lds(gp, lp, 16, 0, 0);
}

// ---------------------------------------------------------------------------
// gemm256p: 256x256 NT GEMM, BK=64, 8 waves (2Mx4N), 2x64KB LDS dbuf split in
// 4 slots/K-tile (A_k0|B_k0|A_k1|B_k1). 4 phases/K-tile with counted vmcnt(4)
// waits (never drains in steady state). 2-way free XOR bank swizzle,
// src-preswizzled. XCD-bijective block swizzle. M%256==0,N%256==0,K%64==0,nwg%8==0.
// ---------------------------------------------------------------------------
template<int OUTBF, int BIASMODE /*0 none,1 col*/, int DORELU>
__global__ __launch_bounds__(512, 2) void gemm256p(
    const short* __restrict__ Ag, const short* __restrict__ Bg,
    void* __restrict__ Cg, const float* __restrict__ bias,
    int K, int N, long long sA, long long sB, long long sC, float scale)
{
    __shared__ short lds[2 * 32768];   // 128 KiB
    const int t = threadIdx.x;
    const int lane = t & 63;
    const int wid = t >> 6;
    const int wm = wid >> 2, wn = wid & 3;

    const int gx = gridDim.x, gy = gridDim.y;
    const int nwg = gx * gy * gridDim.z;
    int id = blockIdx.x + gx * (blockIdx.y + gy * blockIdx.z);
    id = (id & 7) * (nwg >> 3) + (id >> 3);
    const int bx = id % gx;
    const int by = (id / gx) % gy;
    const int bz = id / (gx * gy);

    const long long row0 = (long long)by * 256;
    const long long col0 = (long long)bx * 256;
    const int NT = K >> 6;

    const int srow = t >> 2;
    const int gk = ((t & 3) ^ ((srow >> 1) & 3)) * 8;
    const short* Asrc = Ag + (long long)bz * sA + (row0 + srow) * (long long)K + gk;
    const short* Bsrc = Bg + (long long)bz * sB + (col0 + srow) * (long long)K + gk;
    const long long o128 = 128LL * (long long)K;

    const int frow = lane & 15;
    const int fcol = ((lane >> 4) * 8) ^ (((frow >> 1) & 3) << 3);  // swizzled col (shorts)

    f32x4 acc[8][4] = {};

#define SLOT_STAGE(SB, SRC) do { \
        gld16((SRC), &lds[(SB) + t * 8]); \
        gld16((SRC) + o128, &lds[(SB) + 4096 + t * 8]); } while (0)

    SLOT_STAGE(0,     Asrc);
    SLOT_STAGE(8192,  Bsrc);
    SLOT_STAGE(16384, Asrc + 32);
    SLOT_STAGE(24576, Bsrc + 32);
    asm volatile("s_waitcnt vmcnt(4)\ns_barrier" ::: "memory");

    for (int kt = 0; kt < NT; ++kt) {
        const int rb = (kt & 1) << 15;
        const int wb = ((kt + 1) & 1) << 15;
        const bool st = (kt + 1) < NT;
        const long long kc = (long long)(kt + 1) << 6;

        bf16x8 a0[4], a1[4], b0[4], b1[4];

        // ---- ph0 ----
#pragma unroll
        for (int m = 0; m < 4; ++m)
            a0[m] = *(const bf16x8*)&lds[rb + (wm * 128 + m * 16 + frow) * 32 + fcol];
#pragma unroll
        for (int n = 0; n < 4; ++n)
            b0[n] = *(const bf16x8*)&lds[rb + 8192 + (wn * 64 + n * 16 + frow) * 32 + fcol];
        if (st) SLOT_STAGE(wb, Asrc + kc);
        asm volatile("s_barrier" ::: "memory");
        __builtin_amdgcn_s_setprio(1);
#pragma unroll
        for (int m = 0; m < 4; ++m)
#pragma unroll
            for (int n = 0; n < 4; ++n)
                acc[m][n] = __builtin_amdgcn_mfma_f32_16x16x32_bf16(a0[m], b0[n], acc[m][n], 0, 0, 0);
        __builtin_amdgcn_s_setprio(0);
        asm volatile("s_barrier" ::: "memory");

        // ---- ph1 ----
#pragma unroll
        for (int m = 0; m < 4; ++m)
            a1[m] = *(const bf16x8*)&lds[rb + (wm * 128 + 64 + m * 16 + frow) * 32 + fcol];
        if (st) SLOT_STAGE(wb + 8192, Bsrc + kc);
        asm volatile("s_barrier" ::: "memory");
        __builtin_amdgcn_s_setprio(1);
#pragma unroll
        for (int m = 0; m < 4; ++m)
#pragma unroll
            for (int n = 0; n < 4; ++n)
                acc[4 + m][n] = __builtin_amdgcn_mfma_f32_16x16x32_bf16(a1[m], b0[n], acc[4 + m][n], 0, 0, 0);
        __builtin_amdgcn_s_setprio(0);
        if (st) asm volatile("s_waitcnt vmcnt(4)\ns_barrier" ::: "memory");
        else    asm volatile("s_waitcnt vmcnt(0)\ns_barrier" ::: "memory");

        // ---- ph2 ----
#pragma unroll
        for (int m = 0; m < 4; ++m)
            a0[m] = *(const bf16x8*)&lds[rb + 16384 + (wm * 128 + m * 16 + frow) * 32 + fcol];
#pragma unroll
        for (int n = 0; n < 4; ++n)
            b1[n] = *(const bf16x8*)&lds[rb + 24576 + (wn * 64 + n * 16 + frow) * 32 + fcol];
        if (st) SLOT_STAGE(wb + 16384, Asrc + kc + 32);
        asm volatile("s_barrier" ::: "memory");
        __builtin_amdgcn_s_setprio(1);
#pragma unroll
        for (int m = 0; m < 4; ++m)
#pragma unroll
            for (int n = 0; n < 4; ++n)
                acc[m][n] = __builtin_amdgcn_mfma_f32_16x16x32_bf16(a0[m], b1[n], acc[m][n], 0, 0, 0);
        __builtin_amdgcn_s_setprio(0);
        asm volatile("s_barrier" ::: "memory");

        // ---- ph3 ----
#pragma unroll
        for (int m = 0; m < 4; ++m)
            a1[m] = *(const bf16x8*)&lds[rb + 16384 + (wm * 128 + 64 + m * 16 + frow) * 32 + fcol];
        if (st) SLOT_STAGE(wb + 24576, Bsrc + kc + 32);
        asm volatile("s_barrier" ::: "memory");
        __builtin_amdgcn_s_setprio(1);
#pragma unroll
        for (int m = 0; m < 4; ++m)
#pragma unroll
            for (int n = 0; n < 4; ++n)
                acc[4 + m][n] = __builtin_amdgcn_mfma_f32_16x16x32_bf16(a1[m], b1[n], acc[4 + m][n], 0, 0, 0);
        __builtin_amdgcn_s_setprio(0);
        if (st) asm volatile("s_waitcnt vmcnt(4)\ns_barrier" ::: "memory");
        else    asm volatile("s_barrier" ::: "memory");
    }
#undef SLOT_STAGE

    const int crow = (lane >> 4) * 4;
    const int ccol = lane & 15;
    const long long cz = (long long)bz * sC;
#pragma unroll
    for (int m = 0; m < 8; ++m)
#pragma unroll
        for (int n = 0; n < 4; ++n)
#pragma unroll
            for (int i = 0; i < 4; ++i) {
                long long r = row0 + wm * 128 + m * 16 + crow + i;
                long long c = col0 + wn * 64 + n * 16 + ccol;
                float v = acc[m][n][i] * scale;
                if (BIASMODE == 1) v += bias[c];
                if (DORELU) v = fmaxf(v, 0.0f);
                long long idx = cz + r * (long long)N + c;
                if (OUTBF) ((short*)Cg)[idx] = f2bf(v);
                else ((float*)Cg)[idx] = v;
            }
}

// ---------------------------------------------------------------------------
// NT GEMM: 128x128 tile for small-N matmuls
// ---------------------------------------------------------------------------
template<int OUTBF, int BIASMODE /*0 none,1 col,2 row*/, int DORELU>
__global__ __launch_bounds__(256) void gemm_nt(
    const short* __restrict__ Ag, const short* __restrict__ Bg,
    void* __restrict__ Cg, const float* __restrict__ bias,
    int K, int N, long long sA, long long sB, long long sC, float scale)
{
    __shared__ short lA[128 * 32];
    __shared__ short lB[128 * 32];
    const int t = threadIdx.x;
    const int lane = t & 63;
    const int wave = t >> 6;
    const int wr = (wave >> 1) * 64;
    const int wc = (wave & 1) * 64;
    const long long row0 = (long long)blockIdx.y * 128;
    const long long col0 = (long long)blockIdx.x * 128;
    const short* Ab = Ag + (long long)blockIdx.z * sA + (row0 + (t >> 2)) * (long long)K + (t & 3) * 8;
    const short* Bb = Bg + (long long)blockIdx.z * sB + (col0 + (t >> 2)) * (long long)K + (t & 3) * 8;
    const int frow = lane & 15;
    const int fk = (lane >> 4) * 8;

    f32x4 acc[4][4] = {};
    for (int k0 = 0; k0 < K; k0 += 32) {
        if (k0) __syncthreads();
        gld16(Ab + k0, &lA[t * 8]);
        gld16(Ab + 64LL * K + k0, &lA[2048 + t * 8]);
        gld16(Bb + k0, &lB[t * 8]);
        gld16(Bb + 64LL * K + k0, &lB[2048 + t * 8]);
        __syncthreads();
        bf16x8 af[4], bb[4];
#pragma unroll
        for (int m = 0; m < 4; ++m)
            af[m] = *(const bf16x8*)&lA[(wr + m * 16 + frow) * 32 + fk];
#pragma unroll
        for (int n = 0; n < 4; ++n)
            bb[n] = *(const bf16x8*)&lB[(wc + n * 16 + frow) * 32 + fk];
#pragma unroll
        for (int m = 0; m < 4; ++m)
#pragma unroll
            for (int n = 0; n < 4; ++n)
                acc[m][n] = __builtin_amdgcn_mfma_f32_16x16x32_bf16(af[m], bb[n], acc[m][n], 0, 0, 0);
    }

    const int crow = (lane >> 4) * 4;
    const int ccol = lane & 15;
    const long long cz = (long long)blockIdx.z * sC;
#pragma unroll
    for (int m = 0; m < 4; ++m)
#pragma unroll
        for (int n = 0; n < 4; ++n)
#pragma unroll
            for (int i = 0; i < 4; ++i) {
                long long r = row0 + wr + m * 16 + crow + i;
                long long c = col0 + wc + n * 16 + ccol;
                float v = acc[m][n][i] * scale;
                if (BIASMODE == 1) v += bias[c];
                if (BIASMODE == 2) v += bias[r];
                if (DORELU) v = fmaxf(v, 0.0f);
                long long idx = cz + r * (long long)N + c;
                if (OUTBF) ((short*)Cg)[idx] = f2bf(v);
                else ((float*)Cg)[idx] = v;
            }
}

// fp32 -> bf16 straight cast
__global__ __launch_bounds__(256) void cast_kernel(
    const float* __restrict__ in, short* __restrict__ out, long long n)
{
    long long i = ((long long)blockIdx.x * 256 + threadIdx.x) * 4;
    if (i + 3 < n) {
        float4 v = *(const float4*)&in[i];
        short4 o;
        o.x = f2bf(v.x); o.y = f2bf(v.y); o.z = f2bf(v.z); o.w = f2bf(v.w);
        *(short4*)&out[i] = o;
    }
}

// fp32 [R,C] -> bf16 [C,R], per-batch strides. 64x64 LDS tile.
__global__ __launch_bounds__(256) void transpose_cast(
    const float* __restrict__ in, short* __restrict__ out,
    int R, int C, long long sIn, long long sOut)
{
    __shared__ float tile[64][65];
    const long long zi = (long long)blockIdx.z * sIn;
    const long long zo = (long long)blockIdx.z * sOut;
    const int r0 = blockIdx.y * 64, c0 = blockIdx.x * 64;
    const int lr = threadIdx.x >> 6, lc = threadIdx.x & 63;
#pragma unroll
    for (int i = 0; i < 16; ++i) {
        int r = lr * 16 + i;
        tile[r][lc] = in[zi + (long long)(r0 + r) * C + c0 + lc];
    }
    __syncthreads();
#pragma unroll
    for (int i = 0; i < 16; ++i) {
        int r = lr * 16 + i;
        out[zo + (long long)(c0 + r) * R + r0 + lc] = f2bf(tile[lc][r]);
    }
}

// blended dual softmax over rows of length 2048
__global__ __launch_bounds__(256) void softmax_blend(
    const short* __restrict__ attb, const short* __restrict__ mixb,
    const float* __restrict__ a1p,
    float* __restrict__ outF, short* __restrict__ outB)
{
    const int S = 2048;
    const long long row = blockIdx.x;
    const short* ar = attb + row * S;
    const short* mr = mixb + row * S;
    const int t = threadIdx.x;
    const int wave = t >> 6;

    bf16x8 a8 = *(const bf16x8*)&ar[t * 8];
    bf16x8 m8 = *(const bf16x8*)&mr[t * 8];
    float av[8], mv[8];
#pragma unroll
    for (int i = 0; i < 8; ++i) { av[i] = bf2f(a8[i]); mv[i] = bf2f(m8[i]); }

    float amax = av[0], mmax = mv[0];
#pragma unroll
    for (int i = 1; i < 8; ++i) { amax = fmaxf(amax, av[i]); mmax = fmaxf(mmax, mv[i]); }
#pragma unroll
    for (int o = 32; o; o >>= 1) {
        amax = fmaxf(amax, __shfl_xor(amax, o));
        mmax = fmaxf(mmax, __shfl_xor(mmax, o));
    }
    __shared__ float red[2][4];
    if ((t & 63) == 0) { red[0][wave] = amax; red[1][wave] = mmax; }
    __syncthreads();
    amax = fmaxf(fmaxf(red[0][0], red[0][1]), fmaxf(red[0][2], red[0][3]));
    mmax = fmaxf(fmaxf(red[1][0], red[1][1]), fmaxf(red[1][2], red[1][3]));

    float asum = 0.f, msum = 0.f;
#pragma unroll
    for (int i = 0; i < 8; ++i) {
        av[i] = __expf(av[i] - amax); asum += av[i];
        mv[i] = __expf(mv[i] - mmax); msum += mv[i];
    }
#pragma unroll
    for (int o = 32; o; o >>= 1) {
        asum += __shfl_xor(asum, o);
        msum += __shfl_xor(msum, o);
    }
    __shared__ float red2[2][4];
    if ((t & 63) == 0) { red2[0][wave] = asum; red2[1][wave] = msum; }
    __syncthreads();
    asum = red2[0][0] + red2[0][1] + red2[0][2] + red2[0][3];
    msum = red2[1][0] + red2[1][1] + red2[1][2] + red2[1][3];

    const float a1 = a1p[0];
    const float wm = a1 / msum;
    const float wa = (1.0f - a1) / asum;

    float o0[8];
    bf16x8 ob;
#pragma unroll
    for (int i = 0; i < 8; ++i) {
        float s = wm * mv[i] + wa * av[i];
        o0[i] = s;
        ob[i] = f2bf(s);
    }
    float4 f0, f1;
    f0.x = o0[0]; f0.y = o0[1]; f0.z = o0[2]; f0.w = o0[3];
    f1.x = o0[4]; f1.y = o0[5]; f1.z = o0[6]; f1.w = o0[7];
    *(float4*)&outF[row * S + t * 8] = f0;
    *(float4*)&outF[row * S + t * 8 + 4] = f1;
    *(bf16x8*)&outB[row * S + t * 8] = ob;
}

// LayerNorm over D=384 of (X + Yr); one wave per row, 4 rows/block
template<int WRITE_BF>
__global__ __launch_bounds__(256) void ln_kernel(
    const float* __restrict__ X, const float* __restrict__ Yr,
    const float* __restrict__ g, const float* __restrict__ be,
    float* __restrict__ outF, short* __restrict__ outB)
{
    const int Dm = 384;
    const int wave = threadIdx.x >> 6, lane = threadIdx.x & 63;
    const long long row = (long long)blockIdx.x * 4 + wave;
    const float* x = X + row * Dm;
    const float* y = Yr + row * Dm;
    float h[6];
    float s = 0.f, s2 = 0.f;
#pragma unroll
    for (int j = 0; j < 6; ++j) {
        int c = j * 64 + lane;
        h[j] = x[c] + y[c];
        s += h[j]; s2 += h[j] * h[j];
    }
#pragma unroll
    for (int o = 32; o; o >>= 1) { s += __shfl_xor(s, o); s2 += __shfl_xor(s2, o); }
    const float mean = s * (1.0f / 384.0f);
    const float var = s2 * (1.0f / 384.0f) - mean * mean;
    const float rstd = rsqrtf(var + 1e-5f);
#pragma unroll
    for (int j = 0; j < 6; ++j) {
        int c = j * 64 + lane;
        float v = (h[j] - mean) * rstd * g[c] + be[c];
        outF[row * Dm + c] = v;
        if (WRITE_BF) outB[row * Dm + c] = f2bf(v);
    }
}

extern "C" void kernel_launch(void* const* d_in, const int* in_sizes, int n_in,
                              void* d_out, int out_size, void* d_ws, size_t ws_size,
                              hipStream_t stream) {
    const float* tgt     = (const float*)d_in[0];
    const float* memory  = (const float*)d_in[1];
    const float* a1      = (const float*)d_in[2];
    const float* score_c = (const float*)d_in[3];
    const float* out_c   = (const float*)d_in[4];
    const float* Wq = (const float*)d_in[5];  const float* bq = (const float*)d_in[6];
    const float* Wk = (const float*)d_in[7];  const float* bk = (const float*)d_in[8];
    const float* Wv = (const float*)d_in[9];  const float* bv = (const float*)d_in[10];
    const float* Wu = (const float*)d_in[11]; const float* bu = (const float*)d_in[12];
    const float* Wn = (const float*)d_in[13]; const float* bn = (const float*)d_in[14];
    const float* W1 = (const float*)d_in[15]; const float* b1 = (const float*)d_in[16];
    const float* W2 = (const float*)d_in[17]; const float* b2 = (const float*)d_in[18];
    const float* g1 = (const float*)d_in[19]; const float* be1 = (const float*)d_in[20];
    const float* g2 = (const float*)d_in[21]; const float* be2 = (const float*)d_in[22];

    const long long BT = 16384;            // B*T
    const long long S2 = 2048LL * 2048;    // per-batch score matrix elems
    const long long PB = 2048LL * 384;     // per-batch [2048,384] panel elems
    char* ws = (char*)d_ws;
    size_t off = 0;
    auto A_ = [&](size_t b) { size_t r = off; off += (b + 255) & ~(size_t)255; return r; };

    const size_t oTgtB = A_(BT * 384 * 2);
    const size_t oMemB = A_(BT * 256 * 2);
    const size_t oOutcB = A_(BT * 384 * 2);
    const size_t oWqT = A_(384 * 384 * 2);
    const size_t oWuT = A_(384 * 384 * 2);
    const size_t oWnT = A_(384 * 384 * 2);
    const size_t oWkT = A_(384 * 256 * 2);
    const size_t oWvT = A_(384 * 256 * 2);
    const size_t oW1T = A_(1536 * 384 * 2);
    const size_t oW2T = A_(384 * 1536 * 2);
    const size_t oQU  = A_(16 * PB * 2);  // q (batches 0-7), unknow (8-15)
    const size_t oKP  = A_(16 * PB * 2);  // k (batches 0-7), Pt (8-15)
    const size_t oVT  = A_(8LL * 384 * 2048 * 2);
    const size_t oJ   = A_(8 * S2 * 2);   // score_bf (blend output)
    const size_t oKr  = A_(8 * S2 * 2);   // scoreCt bf16; later z fp32
    const size_t oAM  = A_(16 * S2 * 2);  // knoT early; att (0-7) + mixed (8-15); later h_bf / ff_f
    const size_t oX   = A_(BT * 384 * 4);
    const size_t oXB  = A_(BT * 384 * 2);

    short* tgt_bf  = (short*)(ws + oTgtB);
    short* mem_bf  = (short*)(ws + oMemB);
    short* outc_bf = (short*)(ws + oOutcB);
    short* WqT = (short*)(ws + oWqT);
    short* WuT = (short*)(ws + oWuT);
    short* WnT = (short*)(ws + oWnT);
    short* WkT = (short*)(ws + oWkT);
    short* WvT = (short*)(ws + oWvT);
    short* W1T = (short*)(ws + oW1T);
    short* W2T = (short*)(ws + oW2T);
    short* q_bf   = (short*)(ws + oQU);
    short* unk_bf = q_bf + 8 * PB;
    short* k_bf   = (short*)(ws + oKP);
    short* Pt_bf  = k_bf + 8 * PB;
    short* vT_bf  = (short*)(ws + oVT);
    short* score_bf = (short*)(ws + oJ);
    short* scoreCt  = (short*)(ws + oKr);
    float* z_f      = (float*)(ws + oKr);   // alias (scoreCt dead after Pt GEMM)
    short* knoT_bf  = (short*)(ws + oAM);   // alias: dead before att written
    short* att_bf   = (short*)(ws + oAM);
    short* mix_bf   = att_bf + 8 * S2;
    short* h_bf     = (short*)(ws + oAM);               // alias (att dead after blend)
    float* ff_f     = (float*)(ws + oAM + 8 * S2 * 2);  // alias (mixed dead after blend)
    float* x_f  = (float*)(ws + oX);
    short* x_bf = (short*)(ws + oXB);

    float* outMain = (float*)d_out;
    float* outScore = (float*)d_out + 6291456;   // B*T*D elements

    const float SC = 0.05103103630798288f;  // 1/sqrt(384)
    dim3 blk(256);
    dim3 blk512(512);

    // casts
    cast_kernel<<<6144, blk, 0, stream>>>(tgt, tgt_bf, BT * 384);
    cast_kernel<<<4096, blk, 0, stream>>>(memory, mem_bf, BT * 256);
    cast_kernel<<<6144, blk, 0, stream>>>(out_c, outc_bf, BT * 384);
    // weight transposes ([K,N] -> [N,K] bf16)
    transpose_cast<<<dim3(6, 6, 1), blk, 0, stream>>>(Wq, WqT, 384, 384, 0, 0);
    transpose_cast<<<dim3(6, 4, 1), blk, 0, stream>>>(Wk, WkT, 256, 384, 0, 0);
    transpose_cast<<<dim3(6, 4, 1), blk, 0, stream>>>(Wv, WvT, 256, 384, 0, 0);
    transpose_cast<<<dim3(6, 6, 1), blk, 0, stream>>>(Wu, WuT, 384, 384, 0, 0);
    transpose_cast<<<dim3(6, 6, 1), blk, 0, stream>>>(Wn, WnT, 384, 384, 0, 0);
    transpose_cast<<<dim3(24, 6, 1), blk, 0, stream>>>(W1, W1T, 384, 1536, 0, 0);
    transpose_cast<<<dim3(6, 24, 1), blk, 0, stream>>>(W2, W2T, 1536, 384, 0, 0);
    // score_c^T per batch
    transpose_cast<<<dim3(32, 32, 8), blk, 0, stream>>>(score_c, scoreCt, 2048, 2048, S2, S2);

    // projections (bf16 out)
    gemm_nt<1, 1, 0><<<dim3(3, 128, 1), blk, 0, stream>>>(tgt_bf, WqT, q_bf, bq, 384, 384, 0, 0, 0, 1.0f);
    gemm_nt<1, 1, 0><<<dim3(3, 128, 1), blk, 0, stream>>>(mem_bf, WkT, k_bf, bk, 256, 384, 0, 0, 0, 1.0f);
    gemm_nt<1, 2, 0><<<dim3(16, 3, 8), blk, 0, stream>>>(WvT, mem_bf, vT_bf, bv, 256, 2048,
                                                         0, 2048LL * 256, 384LL * 2048, 1.0f);
    gemm_nt<1, 1, 0><<<dim3(3, 128, 1), blk, 0, stream>>>(tgt_bf, WuT, unk_bf, bu, 384, 384, 0, 0, 0, 1.0f);
    // knoT[d,t] = know[t,d]^T  (same pattern as vT)
    gemm_nt<1, 2, 0><<<dim3(16, 3, 8), blk, 0, stream>>>(WnT, outc_bf, knoT_bf, bn, 384, 2048,
                                                         0, PB, 384LL * 2048, 1.0f);

    // Pt[s,d] = sum_c score_c[c,s] * know[c,d]   (reassociated path)
    gemm_nt<1, 0, 0><<<dim3(3, 16, 8), blk, 0, stream>>>(scoreCt, knoT_bf, Pt_bf, nullptr, 2048, 384,
                                                         S2, 384LL * 2048, PB, 1.0f);
    // combined: batches 0-7: att = SC*q@k^T ; batches 8-15: mixed = SC*unk@Pt^T
    gemm256p<1, 0, 0><<<dim3(8, 8, 16), blk512, 0, stream>>>(q_bf, k_bf, att_bf, nullptr, 384, 2048,
                                                             PB, PB, S2, SC);
    // score = a1*softmax(mixed) + (1-a1)*softmax(att)
    softmax_blend<<<16384, blk, 0, stream>>>(att_bf, mix_bf, a1, outScore, score_bf);
    // z = score @ v
    gemm_nt<0, 0, 0><<<dim3(3, 16, 8), blk, 0, stream>>>(score_bf, vT_bf, z_f, nullptr, 2048, 384,
                                                         S2, 384LL * 2048, PB, 1.0f);
    // x = LN(tgt + z)
    ln_kernel<1><<<4096, blk, 0, stream>>>(tgt, z_f, g1, be1, x_f, x_bf);
    // FFN
    gemm256p<1, 1, 1><<<dim3(6, 64, 1), blk512, 0, stream>>>(x_bf, W1T, h_bf, b1, 384, 1536, 0, 0, 0, 1.0f);
    gemm_nt<0, 1, 0><<<dim3(3, 128, 1), blk, 0, stream>>>(h_bf, W2T, ff_f, b2, 1536, 384, 0, 0, 0, 1.0f);
    // out = LN(x + ff)
    ln_kernel<0><<<4096, blk, 0, stream>>>(x_f, ff_f, g2, be2, outMain, nullptr);
}

// Round 5
// 480.703 us; speedup vs baseline: 1.3924x; 1.0923x over previous
//
#include <hip/hip_runtime.h>
#include <stdint.h>

typedef __attribute__((ext_vector_type(8))) short bf16x8;
typedef __attribute__((ext_vector_type(4))) float f32x4;

__device__ __forceinline__ short f2bf(float f) {
    union { float f; unsigned u; } v; v.f = f;
    unsigned r = v.u + 0x7fffu + ((v.u >> 16) & 1u);
    return (short)(r >> 16);
}
__device__ __forceinline__ float bf2f(short s) {
    union { unsigned u; float f; } v;
    v.u = ((unsigned)(unsigned short)s) << 16;
    return v.f;
}

__device__ __forceinline__ void gld16(const void* g, void* l) {
    auto gp = reinterpret_cast<const __attribute__((address_space(1))) unsigned int*>(
        reinterpret_cast<uintptr_t>(g));
    auto lp = reinterpret_cast<__attribute__((address_space(3))) unsigned int*>(
        reinterpret_cast<uintptr_t>(l));
    __builtin_amdgcn_global_load_lds(gp, lp, 16, 0, 0);
}

// ---------------------------------------------------------------------------
// gemm128p: 128x128 NT GEMM, BK=64, 4 waves (2Mx2N, 64x64 each), 64 KiB LDS
// double-buffer -> 2 blocks/CU (two independent barrier domains per CU cover
// each other's stalls). 2 phases per K-tile:
//   ph0 {ds_read ks0 frags || stage A(kt+1) -> bar -> prio1 -> 16 MFMA -> prio0 -> bar}
//   ph1 {ds_read ks1 frags || stage B(kt+1) -> ... -> vmcnt(0)+bar}
// LDS rows are 128 B = 8x16B segs; swizzle seg ^= (row&7) (2 lanes/bank, free).
// Source pre-swizzled, read swizzled (same involution), gld16 dest linear.
// C[M,N] = scale*(A[M,K] @ B[N,K]^T)(+bias)(+relu).
// Requires M%128==0, N%128==0, K%64==0, nwg%8==0.
// ---------------------------------------------------------------------------
template<int OUTBF, int BIASMODE /*0 none,1 col,2 row*/, int DORELU>
__global__ __launch_bounds__(256, 2) void gemm128p(
    const short* __restrict__ Ag, const short* __restrict__ Bg,
    void* __restrict__ Cg, const float* __restrict__ bias,
    int K, int N, long long sA, long long sB, long long sC, float scale)
{
    __shared__ short lds[2 * 16384];   // 64 KiB: per buf A[128][64] + B[128][64]
    const int t = threadIdx.x;
    const int lane = t & 63;
    const int wave = t >> 6;
    const int wm = wave >> 1, wn = wave & 1;

    // XCD-aware bijective swizzle (nwg % 8 == 0 by launch config)
    const int gx = gridDim.x, gy = gridDim.y;
    const int nwg = gx * gy * gridDim.z;
    int id = blockIdx.x + gx * (blockIdx.y + gy * blockIdx.z);
    id = (id & 7) * (nwg >> 3) + (id >> 3);
    const int bx = id % gx;
    const int by = (id / gx) % gy;
    const int bz = id / (gx * gy);

    const long long row0 = (long long)by * 128;
    const long long col0 = (long long)bx * 128;
    const int NT = K >> 6;

    // staging: thread t covers seg (t&7), rows (t>>3)+32r, r=0..3.
    // source col pre-swizzled so swizzled reads see correct data.
    const int srow = t >> 3;                       // 0..31
    const int gk = ((t & 7) ^ (srow & 7)) * 8;     // swizzled source col (shorts)
    const short* Asrc = Ag + (long long)bz * sA + (row0 + srow) * (long long)K + gk;
    const short* Bsrc = Bg + (long long)bz * sB + (col0 + srow) * (long long)K + gk;

    const int frow = lane & 15;
    const int fq = lane >> 4;                      // 0..3 (16B column block)

    f32x4 acc[4][4] = {};

#define STAGE_A(WB, KC) do { _Pragma("unroll") \
        for (int r = 0; r < 4; ++r) \
            gld16(Asrc + (KC) + (long long)r * 32 * K, &lds[(WB) + t * 8 + r * 2048]); } while (0)
#define STAGE_B(WB, KC) do { _Pragma("unroll") \
        for (int r = 0; r < 4; ++r) \
            gld16(Bsrc + (KC) + (long long)r * 32 * K, &lds[(WB) + 8192 + t * 8 + r * 2048]); } while (0)

    // swizzled fragment read: row*64 + ((ks*4+fq)^(row&7))*8 shorts
#define RD_A(RB, M, KS) (*(const bf16x8*)&lds[(RB) + (wm * 64 + (M) * 16 + frow) * 64 + \
        ((((KS) << 2) | fq) ^ (frow & 7)) * 8])
#define RD_B(RB, Nn, KS) (*(const bf16x8*)&lds[(RB) + 8192 + (wn * 64 + (Nn) * 16 + frow) * 64 + \
        ((((KS) << 2) | fq) ^ (frow & 7)) * 8])

    STAGE_A(0, 0);
    STAGE_B(0, 0);
    asm volatile("s_waitcnt vmcnt(0)\ns_barrier" ::: "memory");

    for (int kt = 0; kt < NT; ++kt) {
        const int rb = (kt & 1) << 14;
        const int wb = ((kt + 1) & 1) << 14;
        const bool st = (kt + 1) < NT;
        const long long kc = (long long)(kt + 1) << 6;

        bf16x8 av[4], bv[4];

        // ---- ph0: ks=0 ----
#pragma unroll
        for (int m = 0; m < 4; ++m) av[m] = RD_A(rb, m, 0);
#pragma unroll
        for (int n = 0; n < 4; ++n) bv[n] = RD_B(rb, n, 0);
        if (st) STAGE_A(wb, kc);
        asm volatile("s_barrier" ::: "memory");
        __builtin_amdgcn_s_setprio(1);
#pragma unroll
        for (int m = 0; m < 4; ++m)
#pragma unroll
            for (int n = 0; n < 4; ++n)
                acc[m][n] = __builtin_amdgcn_mfma_f32_16x16x32_bf16(av[m], bv[n], acc[m][n], 0, 0, 0);
        __builtin_amdgcn_s_setprio(0);
        asm volatile("s_barrier" ::: "memory");

        // ---- ph1: ks=1 ----
#pragma unroll
        for (int m = 0; m < 4; ++m) av[m] = RD_A(rb, m, 1);
#pragma unroll
        for (int n = 0; n < 4; ++n) bv[n] = RD_B(rb, n, 1);
        if (st) STAGE_B(wb, kc);
        asm volatile("s_barrier" ::: "memory");
        __builtin_amdgcn_s_setprio(1);
#pragma unroll
        for (int m = 0; m < 4; ++m)
#pragma unroll
            for (int n = 0; n < 4; ++n)
                acc[m][n] = __builtin_amdgcn_mfma_f32_16x16x32_bf16(av[m], bv[n], acc[m][n], 0, 0, 0);
        __builtin_amdgcn_s_setprio(0);
        if (st) asm volatile("s_waitcnt vmcnt(0)\ns_barrier" ::: "memory");
        else    asm volatile("s_barrier" ::: "memory");
    }
#undef STAGE_A
#undef STAGE_B
#undef RD_A
#undef RD_B

    // epilogue
    const int crow = (lane >> 4) * 4;
    const int ccol = lane & 15;
    const long long cz = (long long)bz * sC;
#pragma unroll
    for (int m = 0; m < 4; ++m)
#pragma unroll
        for (int n = 0; n < 4; ++n)
#pragma unroll
            for (int i = 0; i < 4; ++i) {
                long long r = row0 + wm * 64 + m * 16 + crow + i;
                long long c = col0 + wn * 64 + n * 16 + ccol;
                float v = acc[m][n][i] * scale;
                if (BIASMODE == 1) v += bias[c];
                if (BIASMODE == 2) v += bias[r];
                if (DORELU) v = fmaxf(v, 0.0f);
                long long idx = cz + r * (long long)N + c;
                if (OUTBF) ((short*)Cg)[idx] = f2bf(v);
                else ((float*)Cg)[idx] = v;
            }
}

// fp32 -> bf16 straight cast
__global__ __launch_bounds__(256) void cast_kernel(
    const float* __restrict__ in, short* __restrict__ out, long long n)
{
    long long i = ((long long)blockIdx.x * 256 + threadIdx.x) * 4;
    if (i + 3 < n) {
        float4 v = *(const float4*)&in[i];
        short4 o;
        o.x = f2bf(v.x); o.y = f2bf(v.y); o.z = f2bf(v.z); o.w = f2bf(v.w);
        *(short4*)&out[i] = o;
    }
}

// fp32 [R,C] -> bf16 [C,R], per-batch strides. 64x64 LDS tile.
__global__ __launch_bounds__(256) void transpose_cast(
    const float* __restrict__ in, short* __restrict__ out,
    int R, int C, long long sIn, long long sOut)
{
    __shared__ float tile[64][65];
    const long long zi = (long long)blockIdx.z * sIn;
    const long long zo = (long long)blockIdx.z * sOut;
    const int r0 = blockIdx.y * 64, c0 = blockIdx.x * 64;
    const int lr = threadIdx.x >> 6, lc = threadIdx.x & 63;
#pragma unroll
    for (int i = 0; i < 16; ++i) {
        int r = lr * 16 + i;
        tile[r][lc] = in[zi + (long long)(r0 + r) * C + c0 + lc];
    }
    __syncthreads();
#pragma unroll
    for (int i = 0; i < 16; ++i) {
        int r = lr * 16 + i;
        out[zo + (long long)(c0 + r) * R + r0 + lc] = f2bf(tile[lc][r]);
    }
}

// blended dual softmax over rows of length 2048
__global__ __launch_bounds__(256) void softmax_blend(
    const short* __restrict__ attb, const short* __restrict__ mixb,
    const float* __restrict__ a1p,
    float* __restrict__ outF, short* __restrict__ outB)
{
    const int S = 2048;
    const long long row = blockIdx.x;
    const short* ar = attb + row * S;
    const short* mr = mixb + row * S;
    const int t = threadIdx.x;
    const int wave = t >> 6;

    bf16x8 a8 = *(const bf16x8*)&ar[t * 8];
    bf16x8 m8 = *(const bf16x8*)&mr[t * 8];
    float av[8], mv[8];
#pragma unroll
    for (int i = 0; i < 8; ++i) { av[i] = bf2f(a8[i]); mv[i] = bf2f(m8[i]); }

    float amax = av[0], mmax = mv[0];
#pragma unroll
    for (int i = 1; i < 8; ++i) { amax = fmaxf(amax, av[i]); mmax = fmaxf(mmax, mv[i]); }
#pragma unroll
    for (int o = 32; o; o >>= 1) {
        amax = fmaxf(amax, __shfl_xor(amax, o));
        mmax = fmaxf(mmax, __shfl_xor(mmax, o));
    }
    __shared__ float red[2][4];
    if ((t & 63) == 0) { red[0][wave] = amax; red[1][wave] = mmax; }
    __syncthreads();
    amax = fmaxf(fmaxf(red[0][0], red[0][1]), fmaxf(red[0][2], red[0][3]));
    mmax = fmaxf(fmaxf(red[1][0], red[1][1]), fmaxf(red[1][2], red[1][3]));

    float asum = 0.f, msum = 0.f;
#pragma unroll
    for (int i = 0; i < 8; ++i) {
        av[i] = __expf(av[i] - amax); asum += av[i];
        mv[i] = __expf(mv[i] - mmax); msum += mv[i];
    }
#pragma unroll
    for (int o = 32; o; o >>= 1) {
        asum += __shfl_xor(asum, o);
        msum += __shfl_xor(msum, o);
    }
    __shared__ float red2[2][4];
    if ((t & 63) == 0) { red2[0][wave] = asum; red2[1][wave] = msum; }
    __syncthreads();
    asum = red2[0][0] + red2[0][1] + red2[0][2] + red2[0][3];
    msum = red2[1][0] + red2[1][1] + red2[1][2] + red2[1][3];

    const float a1 = a1p[0];
    const float wm = a1 / msum;
    const float wa = (1.0f - a1) / asum;

    float o0[8];
    bf16x8 ob;
#pragma unroll
    for (int i = 0; i < 8; ++i) {
        float s = wm * mv[i] + wa * av[i];
        o0[i] = s;
        ob[i] = f2bf(s);
    }
    float4 f0, f1;
    f0.x = o0[0]; f0.y = o0[1]; f0.z = o0[2]; f0.w = o0[3];
    f1.x = o0[4]; f1.y = o0[5]; f1.z = o0[6]; f1.w = o0[7];
    *(float4*)&outF[row * S + t * 8] = f0;
    *(float4*)&outF[row * S + t * 8 + 4] = f1;
    *(bf16x8*)&outB[row * S + t * 8] = ob;
}

// LayerNorm over D=384 of (X + Yr); one wave per row, 4 rows/block
template<int WRITE_BF>
__global__ __launch_bounds__(256) void ln_kernel(
    const float* __restrict__ X, const float* __restrict__ Yr,
    const float* __restrict__ g, const float* __restrict__ be,
    float* __restrict__ outF, short* __restrict__ outB)
{
    const int Dm = 384;
    const int wave = threadIdx.x >> 6, lane = threadIdx.x & 63;
    const long long row = (long long)blockIdx.x * 4 + wave;
    const float* x = X + row * Dm;
    const float* y = Yr + row * Dm;
    float h[6];
    float s = 0.f, s2 = 0.f;
#pragma unroll
    for (int j = 0; j < 6; ++j) {
        int c = j * 64 + lane;
        h[j] = x[c] + y[c];
        s += h[j]; s2 += h[j] * h[j];
    }
#pragma unroll
    for (int o = 32; o; o >>= 1) { s += __shfl_xor(s, o); s2 += __shfl_xor(s2, o); }
    const float mean = s * (1.0f / 384.0f);
    const float var = s2 * (1.0f / 384.0f) - mean * mean;
    const float rstd = rsqrtf(var + 1e-5f);
#pragma unroll
    for (int j = 0; j < 6; ++j) {
        int c = j * 64 + lane;
        float v = (h[j] - mean) * rstd * g[c] + be[c];
        outF[row * Dm + c] = v;
        if (WRITE_BF) outB[row * Dm + c] = f2bf(v);
    }
}

extern "C" void kernel_launch(void* const* d_in, const int* in_sizes, int n_in,
                              void* d_out, int out_size, void* d_ws, size_t ws_size,
                              hipStream_t stream) {
    const float* tgt     = (const float*)d_in[0];
    const float* memory  = (const float*)d_in[1];
    const float* a1      = (const float*)d_in[2];
    const float* score_c = (const float*)d_in[3];
    const float* out_c   = (const float*)d_in[4];
    const float* Wq = (const float*)d_in[5];  const float* bq = (const float*)d_in[6];
    const float* Wk = (const float*)d_in[7];  const float* bk = (const float*)d_in[8];
    const float* Wv = (const float*)d_in[9];  const float* bv = (const float*)d_in[10];
    const float* Wu = (const float*)d_in[11]; const float* bu = (const float*)d_in[12];
    const float* Wn = (const float*)d_in[13]; const float* bn = (const float*)d_in[14];
    const float* W1 = (const float*)d_in[15]; const float* b1 = (const float*)d_in[16];
    const float* W2 = (const float*)d_in[17]; const float* b2 = (const float*)d_in[18];
    const float* g1 = (const float*)d_in[19]; const float* be1 = (const float*)d_in[20];
    const float* g2 = (const float*)d_in[21]; const float* be2 = (const float*)d_in[22];

    const long long BT = 16384;            // B*T
    const long long S2 = 2048LL * 2048;    // per-batch score matrix elems
    const long long PB = 2048LL * 384;     // per-batch [2048,384] panel elems
    char* ws = (char*)d_ws;
    size_t off = 0;
    auto A_ = [&](size_t b) { size_t r = off; off += (b + 255) & ~(size_t)255; return r; };

    const size_t oTgtB = A_(BT * 384 * 2);
    const size_t oMemB = A_(BT * 256 * 2);
    const size_t oOutcB = A_(BT * 384 * 2);
    const size_t oWqT = A_(384 * 384 * 2);
    const size_t oWuT = A_(384 * 384 * 2);
    const size_t oWnT = A_(384 * 384 * 2);
    const size_t oWkT = A_(384 * 256 * 2);
    const size_t oWvT = A_(384 * 256 * 2);
    const size_t oW1T = A_(1536 * 384 * 2);
    const size_t oW2T = A_(384 * 1536 * 2);
    const size_t oQU  = A_(16 * PB * 2);  // q (batches 0-7), unknow (8-15)
    const size_t oKP  = A_(16 * PB * 2);  // k (batches 0-7), Pt (8-15)
    const size_t oVT  = A_(8LL * 384 * 2048 * 2);
    const size_t oJ   = A_(8 * S2 * 2);   // score_bf (blend output)
    const size_t oKr  = A_(8 * S2 * 2);   // scoreCt bf16; later z fp32
    const size_t oAM  = A_(16 * S2 * 2);  // knoT early; att (0-7) + mixed (8-15); later h_bf / ff_f
    const size_t oX   = A_(BT * 384 * 4);
    const size_t oXB  = A_(BT * 384 * 2);

    short* tgt_bf  = (short*)(ws + oTgtB);
    short* mem_bf  = (short*)(ws + oMemB);
    short* outc_bf = (short*)(ws + oOutcB);
    short* WqT = (short*)(ws + oWqT);
    short* WuT = (short*)(ws + oWuT);
    short* WnT = (short*)(ws + oWnT);
    short* WkT = (short*)(ws + oWkT);
    short* WvT = (short*)(ws + oWvT);
    short* W1T = (short*)(ws + oW1T);
    short* W2T = (short*)(ws + oW2T);
    short* q_bf   = (short*)(ws + oQU);
    short* unk_bf = q_bf + 8 * PB;
    short* k_bf   = (short*)(ws + oKP);
    short* Pt_bf  = k_bf + 8 * PB;
    short* vT_bf  = (short*)(ws + oVT);
    short* score_bf = (short*)(ws + oJ);
    short* scoreCt  = (short*)(ws + oKr);
    float* z_f      = (float*)(ws + oKr);   // alias (scoreCt dead after Pt GEMM)
    short* knoT_bf  = (short*)(ws + oAM);   // alias: dead before att written
    short* att_bf   = (short*)(ws + oAM);
    short* mix_bf   = att_bf + 8 * S2;
    short* h_bf     = (short*)(ws + oAM);               // alias (att dead after blend)
    float* ff_f     = (float*)(ws + oAM + 8 * S2 * 2);  // alias (mixed dead after blend)
    float* x_f  = (float*)(ws + oX);
    short* x_bf = (short*)(ws + oXB);

    float* outMain = (float*)d_out;
    float* outScore = (float*)d_out + 6291456;   // B*T*D elements

    const float SC = 0.05103103630798288f;  // 1/sqrt(384)
    dim3 blk(256);

    // casts
    cast_kernel<<<6144, blk, 0, stream>>>(tgt, tgt_bf, BT * 384);
    cast_kernel<<<4096, blk, 0, stream>>>(memory, mem_bf, BT * 256);
    cast_kernel<<<6144, blk, 0, stream>>>(out_c, outc_bf, BT * 384);
    // weight transposes ([K,N] -> [N,K] bf16)
    transpose_cast<<<dim3(6, 6, 1), blk, 0, stream>>>(Wq, WqT, 384, 384, 0, 0);
    transpose_cast<<<dim3(6, 4, 1), blk, 0, stream>>>(Wk, WkT, 256, 384, 0, 0);
    transpose_cast<<<dim3(6, 4, 1), blk, 0, stream>>>(Wv, WvT, 256, 384, 0, 0);
    transpose_cast<<<dim3(6, 6, 1), blk, 0, stream>>>(Wu, WuT, 384, 384, 0, 0);
    transpose_cast<<<dim3(6, 6, 1), blk, 0, stream>>>(Wn, WnT, 384, 384, 0, 0);
    transpose_cast<<<dim3(24, 6, 1), blk, 0, stream>>>(W1, W1T, 384, 1536, 0, 0);
    transpose_cast<<<dim3(6, 24, 1), blk, 0, stream>>>(W2, W2T, 1536, 384, 0, 0);
    // score_c^T per batch
    transpose_cast<<<dim3(32, 32, 8), blk, 0, stream>>>(score_c, scoreCt, 2048, 2048, S2, S2);

    // projections (bf16 out)
    gemm128p<1, 1, 0><<<dim3(3, 128, 1), blk, 0, stream>>>(tgt_bf, WqT, q_bf, bq, 384, 384, 0, 0, 0, 1.0f);
    gemm128p<1, 1, 0><<<dim3(3, 128, 1), blk, 0, stream>>>(mem_bf, WkT, k_bf, bk, 256, 384, 0, 0, 0, 1.0f);
    gemm128p<1, 2, 0><<<dim3(16, 3, 8), blk, 0, stream>>>(WvT, mem_bf, vT_bf, bv, 256, 2048,
                                                          0, 2048LL * 256, 384LL * 2048, 1.0f);
    gemm128p<1, 1, 0><<<dim3(3, 128, 1), blk, 0, stream>>>(tgt_bf, WuT, unk_bf, bu, 384, 384, 0, 0, 0, 1.0f);
    // knoT[d,t] = know[t,d]^T  (same pattern as vT)
    gemm128p<1, 2, 0><<<dim3(16, 3, 8), blk, 0, stream>>>(WnT, outc_bf, knoT_bf, bn, 384, 2048,
                                                          0, PB, 384LL * 2048, 1.0f);

    // Pt[s,d] = sum_c score_c[c,s] * know[c,d]   (reassociated path)
    gemm128p<1, 0, 0><<<dim3(3, 16, 8), blk, 0, stream>>>(scoreCt, knoT_bf, Pt_bf, nullptr, 2048, 384,
                                                          S2, 384LL * 2048, PB, 1.0f);
    // combined: batches 0-7: att = SC*q@k^T ; batches 8-15: mixed = SC*unk@Pt^T
    gemm128p<1, 0, 0><<<dim3(16, 16, 16), blk, 0, stream>>>(q_bf, k_bf, att_bf, nullptr, 384, 2048,
                                                            PB, PB, S2, SC);
    // score = a1*softmax(mixed) + (1-a1)*softmax(att)
    softmax_blend<<<16384, blk, 0, stream>>>(att_bf, mix_bf, a1, outScore, score_bf);
    // z = score @ v
    gemm128p<0, 0, 0><<<dim3(3, 16, 8), blk, 0, stream>>>(score_bf, vT_bf, z_f, nullptr, 2048, 384,
                                                          S2, 384LL * 2048, PB, 1.0f);
    // x = LN(tgt + z)
    ln_kernel<1><<<4096, blk, 0, stream>>>(tgt, z_f, g1, be1, x_f, x_bf);
    // FFN
    gemm128p<1, 1, 1><<<dim3(12, 128, 1), blk, 0, stream>>>(x_bf, W1T, h_bf, b1, 384, 1536, 0, 0, 0, 1.0f);
    gemm128p<0, 1, 0><<<dim3(3, 128, 1), blk, 0, stream>>>(h_bf, W2T, ff_f, b2, 1536, 384, 0, 0, 0, 1.0f);
    // out = LN(x + ff)
    ln_kernel<0><<<4096, blk, 0, stream>>>(x_f, ff_f, g2, be2, outMain, nullptr);
}

// Round 6
// 460.367 us; speedup vs baseline: 1.4539x; 1.0442x over previous
//
#include <hip/hip_runtime.h>
#include <stdint.h>

typedef __attribute__((ext_vector_type(8))) short bf16x8;
typedef __attribute__((ext_vector_type(4))) float f32x4;

__device__ __forceinline__ short f2bf(float f) {
    union { float f; unsigned u; } v; v.f = f;
    unsigned r = v.u + 0x7fffu + ((v.u >> 16) & 1u);
    return (short)(r >> 16);
}
__device__ __forceinline__ float bf2f(short s) {
    union { unsigned u; float f; } v;
    v.u = ((unsigned)(unsigned short)s) << 16;
    return v.f;
}

__device__ __forceinline__ void gld16(const void* g, void* l) {
    auto gp = reinterpret_cast<const __attribute__((address_space(1))) unsigned int*>(
        reinterpret_cast<uintptr_t>(g));
    auto lp = reinterpret_cast<__attribute__((address_space(3))) unsigned int*>(
        reinterpret_cast<uintptr_t>(l));
    __builtin_amdgcn_global_load_lds(gp, lp, 16, 0, 0);
}

// ---------------------------------------------------------------------------
// gemm128p: 128x128 NT GEMM, BK=64, 4 waves, 64 KiB LDS dbuf (2 blocks/CU).
// C[m,n] = scale*(sum_k A[m,k]B[n,k]) (+bias)(+relu), explicit lda/ldb/ldc.
// Swizzle: seg ^= row&7 (2 lanes/bank), source pre-swizzled. XCD-bijective
// block swizzle. M%128==0, N%128==0, K%64==0, nwg%8==0.
// ---------------------------------------------------------------------------
template<int OUTBF, int BIASMODE /*0 none,1 col,2 row*/, int DORELU>
__global__ __launch_bounds__(256, 2) void gemm128p(
    const short* __restrict__ Ag, const short* __restrict__ Bg,
    void* __restrict__ Cg, const float* __restrict__ bias,
    int K, int lda, int ldb, int ldc,
    long long sA, long long sB, long long sC, float scale)
{
    __shared__ short lds[2 * 16384];
    const int t = threadIdx.x;
    const int lane = t & 63;
    const int wave = t >> 6;
    const int wm = wave >> 1, wn = wave & 1;

    const int gx = gridDim.x, gy = gridDim.y;
    const int nwg = gx * gy * gridDim.z;
    int id = blockIdx.x + gx * (blockIdx.y + gy * blockIdx.z);
    id = (id & 7) * (nwg >> 3) + (id >> 3);
    const int bx = id % gx;
    const int by = (id / gx) % gy;
    const int bz = id / (gx * gy);

    const long long row0 = (long long)by * 128;
    const long long col0 = (long long)bx * 128;
    const int NT = K >> 6;

    const int srow = t >> 3;
    const int gk = ((t & 7) ^ (srow & 7)) * 8;
    const short* Asrc = Ag + (long long)bz * sA + (row0 + srow) * (long long)lda + gk;
    const short* Bsrc = Bg + (long long)bz * sB + (col0 + srow) * (long long)ldb + gk;

    const int frow = lane & 15;
    const int fq = lane >> 4;

    f32x4 acc[4][4] = {};

#define STAGE_A(WB, KC) do { _Pragma("unroll") \
        for (int r = 0; r < 4; ++r) \
            gld16(Asrc + (KC) + (long long)r * 32 * lda, &lds[(WB) + t * 8 + r * 2048]); } while (0)
#define STAGE_B(WB, KC) do { _Pragma("unroll") \
        for (int r = 0; r < 4; ++r) \
            gld16(Bsrc + (KC) + (long long)r * 32 * ldb, &lds[(WB) + 8192 + t * 8 + r * 2048]); } while (0)
#define RD_A(RB, M, KS) (*(const bf16x8*)&lds[(RB) + (wm * 64 + (M) * 16 + frow) * 64 + \
        ((((KS) << 2) | fq) ^ (frow & 7)) * 8])
#define RD_B(RB, Nn, KS) (*(const bf16x8*)&lds[(RB) + 8192 + (wn * 64 + (Nn) * 16 + frow) * 64 + \
        ((((KS) << 2) | fq) ^ (frow & 7)) * 8])

    STAGE_A(0, 0);
    STAGE_B(0, 0);
    asm volatile("s_waitcnt vmcnt(0)\ns_barrier" ::: "memory");

    for (int kt = 0; kt < NT; ++kt) {
        const int rb = (kt & 1) << 14;
        const int wb = ((kt + 1) & 1) << 14;
        const bool st = (kt + 1) < NT;
        const long long kc = (long long)(kt + 1) << 6;

        bf16x8 av[4], bv[4];

#pragma unroll
        for (int m = 0; m < 4; ++m) av[m] = RD_A(rb, m, 0);
#pragma unroll
        for (int n = 0; n < 4; ++n) bv[n] = RD_B(rb, n, 0);
        if (st) STAGE_A(wb, kc);
        asm volatile("s_barrier" ::: "memory");
        __builtin_amdgcn_s_setprio(1);
#pragma unroll
        for (int m = 0; m < 4; ++m)
#pragma unroll
            for (int n = 0; n < 4; ++n)
                acc[m][n] = __builtin_amdgcn_mfma_f32_16x16x32_bf16(av[m], bv[n], acc[m][n], 0, 0, 0);
        __builtin_amdgcn_s_setprio(0);
        asm volatile("s_barrier" ::: "memory");

#pragma unroll
        for (int m = 0; m < 4; ++m) av[m] = RD_A(rb, m, 1);
#pragma unroll
        for (int n = 0; n < 4; ++n) bv[n] = RD_B(rb, n, 1);
        if (st) STAGE_B(wb, kc);
        asm volatile("s_barrier" ::: "memory");
        __builtin_amdgcn_s_setprio(1);
#pragma unroll
        for (int m = 0; m < 4; ++m)
#pragma unroll
            for (int n = 0; n < 4; ++n)
                acc[m][n] = __builtin_amdgcn_mfma_f32_16x16x32_bf16(av[m], bv[n], acc[m][n], 0, 0, 0);
        __builtin_amdgcn_s_setprio(0);
        if (st) asm volatile("s_waitcnt vmcnt(0)\ns_barrier" ::: "memory");
        else    asm volatile("s_barrier" ::: "memory");
    }
#undef STAGE_A
#undef STAGE_B

    const int crow = (lane >> 4) * 4;
    const int ccol = lane & 15;
    const long long cz = (long long)bz * sC;
#pragma unroll
    for (int m = 0; m < 4; ++m)
#pragma unroll
        for (int n = 0; n < 4; ++n)
#pragma unroll
            for (int i = 0; i < 4; ++i) {
                long long r = row0 + wm * 64 + m * 16 + crow + i;
                long long c = col0 + wn * 64 + n * 16 + ccol;
                float v = acc[m][n][i] * scale;
                if (BIASMODE == 1) v += bias[c];
                if (BIASMODE == 2) v += bias[r];
                if (DORELU) v = fmaxf(v, 0.0f);
                long long idx = cz + r * (long long)ldc + c;
                if (OUTBF) ((short*)Cg)[idx] = f2bf(v);
                else ((float*)Cg)[idx] = v;
            }
}

// ---------------------------------------------------------------------------
// gemm128pz: dual-parameter variant, z<8 -> set 1 (vT), z>=8 -> set 2 (knoT).
// Both: C = A @ B^T + rowbias, A = weight (sA=0), OUTBF=1.
// ---------------------------------------------------------------------------
__global__ __launch_bounds__(256, 2) void gemm128pz(
    const short* __restrict__ A1, const short* __restrict__ B1, short* __restrict__ C1,
    const float* __restrict__ bias1, int K1, int lda1, int ldb1, int ldc1,
    long long sB1, long long sC1,
    const short* __restrict__ A2, const short* __restrict__ B2, short* __restrict__ C2,
    const float* __restrict__ bias2, int K2, int lda2, int ldb2, int ldc2,
    long long sB2, long long sC2)
{
    __shared__ short lds[2 * 16384];
    const int t = threadIdx.x;
    const int lane = t & 63;
    const int wave = t >> 6;
    const int wm = wave >> 1, wn = wave & 1;

    const int gx = gridDim.x, gy = gridDim.y;
    const int nwg = gx * gy * gridDim.z;
    int id = blockIdx.x + gx * (blockIdx.y + gy * blockIdx.z);
    id = (id & 7) * (nwg >> 3) + (id >> 3);
    const int bx = id % gx;
    const int by = (id / gx) % gy;
    const int bz = id / (gx * gy);

    const bool sel = bz >= 8;
    const int zz = bz & 7;
    const short* Ag = sel ? A2 : A1;
    const short* Bg = sel ? B2 : B1;
    short* Cg = sel ? C2 : C1;
    const float* bias = sel ? bias2 : bias1;
    const int K = sel ? K2 : K1;
    const int lda = sel ? lda2 : lda1;
    const int ldb = sel ? ldb2 : ldb1;
    const int ldc = sel ? ldc2 : ldc1;
    const long long sB = sel ? sB2 : sB1;
    const long long sC = sel ? sC2 : sC1;

    const long long row0 = (long long)by * 128;
    const long long col0 = (long long)bx * 128;
    const int NT = K >> 6;

    const int srow = t >> 3;
    const int gk = ((t & 7) ^ (srow & 7)) * 8;
    const short* Asrc = Ag + (row0 + srow) * (long long)lda + gk;
    const short* Bsrc = Bg + (long long)zz * sB + (col0 + srow) * (long long)ldb + gk;

    const int frow = lane & 15;
    const int fq = lane >> 4;

    f32x4 acc[4][4] = {};

#define STAGE_A(WB, KC) do { _Pragma("unroll") \
        for (int r = 0; r < 4; ++r) \
            gld16(Asrc + (KC) + (long long)r * 32 * lda, &lds[(WB) + t * 8 + r * 2048]); } while (0)
#define STAGE_B(WB, KC) do { _Pragma("unroll") \
        for (int r = 0; r < 4; ++r) \
            gld16(Bsrc + (KC) + (long long)r * 32 * ldb, &lds[(WB) + 8192 + t * 8 + r * 2048]); } while (0)

    STAGE_A(0, 0);
    STAGE_B(0, 0);
    asm volatile("s_waitcnt vmcnt(0)\ns_barrier" ::: "memory");

    for (int kt = 0; kt < NT; ++kt) {
        const int rb = (kt & 1) << 14;
        const int wb = ((kt + 1) & 1) << 14;
        const bool st = (kt + 1) < NT;
        const long long kc = (long long)(kt + 1) << 6;

        bf16x8 av[4], bv[4];

#pragma unroll
        for (int m = 0; m < 4; ++m) av[m] = RD_A(rb, m, 0);
#pragma unroll
        for (int n = 0; n < 4; ++n) bv[n] = RD_B(rb, n, 0);
        if (st) STAGE_A(wb, kc);
        asm volatile("s_barrier" ::: "memory");
        __builtin_amdgcn_s_setprio(1);
#pragma unroll
        for (int m = 0; m < 4; ++m)
#pragma unroll
            for (int n = 0; n < 4; ++n)
                acc[m][n] = __builtin_amdgcn_mfma_f32_16x16x32_bf16(av[m], bv[n], acc[m][n], 0, 0, 0);
        __builtin_amdgcn_s_setprio(0);
        asm volatile("s_barrier" ::: "memory");

#pragma unroll
        for (int m = 0; m < 4; ++m) av[m] = RD_A(rb, m, 1);
#pragma unroll
        for (int n = 0; n < 4; ++n) bv[n] = RD_B(rb, n, 1);
        if (st) STAGE_B(wb, kc);
        asm volatile("s_barrier" ::: "memory");
        __builtin_amdgcn_s_setprio(1);
#pragma unroll
        for (int m = 0; m < 4; ++m)
#pragma unroll
            for (int n = 0; n < 4; ++n)
                acc[m][n] = __builtin_amdgcn_mfma_f32_16x16x32_bf16(av[m], bv[n], acc[m][n], 0, 0, 0);
        __builtin_amdgcn_s_setprio(0);
        if (st) asm volatile("s_waitcnt vmcnt(0)\ns_barrier" ::: "memory");
        else    asm volatile("s_barrier" ::: "memory");
    }
#undef STAGE_A
#undef STAGE_B

    const int crow = (lane >> 4) * 4;
    const int ccol = lane & 15;
    const long long cz = (long long)zz * sC;
#pragma unroll
    for (int m = 0; m < 4; ++m)
#pragma unroll
        for (int n = 0; n < 4; ++n)
#pragma unroll
            for (int i = 0; i < 4; ++i) {
                long long r = row0 + wm * 64 + m * 16 + crow + i;
                long long c = col0 + wn * 64 + n * 16 + ccol;
                float v = acc[m][n][i] + bias[r];
                Cg[cz + r * (long long)ldc + c] = f2bf(v);
            }
}

// ---------------------------------------------------------------------------
// gemm128dd: dual-source fused att+mixed. One block computes TWO 128x128
// output tiles at the same (row,col): accA from (A, B), accB from (A+dA,
// B+dB), written to C and C+dC. K per pair; loop runs 2*NT tiles.
// ---------------------------------------------------------------------------
__global__ __launch_bounds__(256, 2) void gemm128dd(
    const short* __restrict__ Ag, const short* __restrict__ Bg, short* __restrict__ Cg,
    int K, int lda, int ldb, int ldc,
    long long sA, long long sB, long long sC,
    int dA, long long dB, long long dC, float scale)
{
    __shared__ short lds[2 * 16384];
    const int t = threadIdx.x;
    const int lane = t & 63;
    const int wave = t >> 6;
    const int wm = wave >> 1, wn = wave & 1;

    const int gx = gridDim.x, gy = gridDim.y;
    const int nwg = gx * gy * gridDim.z;
    int id = blockIdx.x + gx * (blockIdx.y + gy * blockIdx.z);
    id = (id & 7) * (nwg >> 3) + (id >> 3);
    const int bx = id % gx;
    const int by = (id / gx) % gy;
    const int bz = id / (gx * gy);

    const long long row0 = (long long)by * 128;
    const long long col0 = (long long)bx * 128;
    const int NT = K >> 6;

    const int srow = t >> 3;
    const int gk = ((t & 7) ^ (srow & 7)) * 8;
    const short* Asrc = Ag + (long long)bz * sA + (row0 + srow) * (long long)lda + gk;
    const short* Bsrc = Bg + (long long)bz * sB + (col0 + srow) * (long long)ldb + gk;

    const int frow = lane & 15;
    const int fq = lane >> 4;

    f32x4 accA[4][4] = {};
    f32x4 accB[4][4] = {};

    // staging offset for tile index kt2 in [0, 2*NT)
#define AOFF(KT2) (((KT2) >= NT) ? ((long long)dA + (long long)((KT2) - NT) * 64) : ((long long)(KT2) * 64))
#define BOFF(KT2) (((KT2) >= NT) ? (dB + (long long)((KT2) - NT) * 64) : ((long long)(KT2) * 64))
#define STAGE_A(WB, OFF) do { _Pragma("unroll") \
        for (int r = 0; r < 4; ++r) \
            gld16(Asrc + (OFF) + (long long)r * 32 * lda, &lds[(WB) + t * 8 + r * 2048]); } while (0)
#define STAGE_B(WB, OFF) do { _Pragma("unroll") \
        for (int r = 0; r < 4; ++r) \
            gld16(Bsrc + (OFF) + (long long)r * 32 * ldb, &lds[(WB) + 8192 + t * 8 + r * 2048]); } while (0)

    STAGE_A(0, 0);
    STAGE_B(0, 0);
    asm volatile("s_waitcnt vmcnt(0)\ns_barrier" ::: "memory");

    const int NT2 = NT * 2;
    for (int kt = 0; kt < NT2; ++kt) {
        const int rb = (kt & 1) << 14;
        const int wb = ((kt + 1) & 1) << 14;
        const bool st = (kt + 1) < NT2;
        const long long ao = AOFF(kt + 1);
        const long long bo = BOFF(kt + 1);
        const bool first = kt < NT;

        bf16x8 av[4], bv[4];

#pragma unroll
        for (int m = 0; m < 4; ++m) av[m] = RD_A(rb, m, 0);
#pragma unroll
        for (int n = 0; n < 4; ++n) bv[n] = RD_B(rb, n, 0);
        if (st) STAGE_A(wb, ao);
        asm volatile("s_barrier" ::: "memory");
        __builtin_amdgcn_s_setprio(1);
        if (first) {
#pragma unroll
            for (int m = 0; m < 4; ++m)
#pragma unroll
                for (int n = 0; n < 4; ++n)
                    accA[m][n] = __builtin_amdgcn_mfma_f32_16x16x32_bf16(av[m], bv[n], accA[m][n], 0, 0, 0);
        } else {
#pragma unroll
            for (int m = 0; m < 4; ++m)
#pragma unroll
                for (int n = 0; n < 4; ++n)
                    accB[m][n] = __builtin_amdgcn_mfma_f32_16x16x32_bf16(av[m], bv[n], accB[m][n], 0, 0, 0);
        }
        __builtin_amdgcn_s_setprio(0);
        asm volatile("s_barrier" ::: "memory");

#pragma unroll
        for (int m = 0; m < 4; ++m) av[m] = RD_A(rb, m, 1);
#pragma unroll
        for (int n = 0; n < 4; ++n) bv[n] = RD_B(rb, n, 1);
        if (st) STAGE_B(wb, bo);
        asm volatile("s_barrier" ::: "memory");
        __builtin_amdgcn_s_setprio(1);
        if (first) {
#pragma unroll
            for (int m = 0; m < 4; ++m)
#pragma unroll
                for (int n = 0; n < 4; ++n)
                    accA[m][n] = __builtin_amdgcn_mfma_f32_16x16x32_bf16(av[m], bv[n], accA[m][n], 0, 0, 0);
        } else {
#pragma unroll
            for (int m = 0; m < 4; ++m)
#pragma unroll
                for (int n = 0; n < 4; ++n)
                    accB[m][n] = __builtin_amdgcn_mfma_f32_16x16x32_bf16(av[m], bv[n], accB[m][n], 0, 0, 0);
        }
        __builtin_amdgcn_s_setprio(0);
        if (st) asm volatile("s_waitcnt vmcnt(0)\ns_barrier" ::: "memory");
        else    asm volatile("s_barrier" ::: "memory");
    }
#undef STAGE_A
#undef STAGE_B
#undef AOFF
#undef BOFF
#undef RD_A
#undef RD_B

    const int crow = (lane >> 4) * 4;
    const int ccol = lane & 15;
    const long long cz = (long long)bz * sC;
#pragma unroll
    for (int m = 0; m < 4; ++m)
#pragma unroll
        for (int n = 0; n < 4; ++n)
#pragma unroll
            for (int i = 0; i < 4; ++i) {
                long long r = row0 + wm * 64 + m * 16 + crow + i;
                long long c = col0 + wn * 64 + n * 16 + ccol;
                long long idx = cz + r * (long long)ldc + c;
                Cg[idx] = f2bf(accA[m][n][i] * scale);
                Cg[idx + dC] = f2bf(accB[m][n][i] * scale);
            }
}

// fused casts: tgt, memory, out_c -> bf16; concat bq|bu -> qu_bias (fp32)
__global__ __launch_bounds__(256) void cast_all(
    const float* __restrict__ tgt, const float* __restrict__ mem, const float* __restrict__ outc,
    const float* __restrict__ bq, const float* __restrict__ bu,
    short* __restrict__ tgtb, short* __restrict__ memb, short* __restrict__ outcb,
    float* __restrict__ qubias)
{
    const long long R1 = 1572864;            // tgt f4
    const long long R2 = R1 + 1048576;       // memory f4
    const long long R3 = R2 + 1572864;       // out_c f4
    const long long R4 = R3 + 192;           // bias f4
    long long i = (long long)blockIdx.x * 256 + threadIdx.x;
    const float* in; short* out; long long j;
    if (i < R1) { in = tgt; out = tgtb; j = i; }
    else if (i < R2) { in = mem; out = memb; j = i - R1; }
    else if (i < R3) { in = outc; out = outcb; j = i - R2; }
    else if (i < R4) {
        j = i - R3;
        ((float4*)qubias)[j] = (j < 96) ? ((const float4*)bq)[j] : ((const float4*)bu)[j - 96];
        return;
    } else return;
    float4 v = ((const float4*)in)[j];
    short4 o;
    o.x = f2bf(v.x); o.y = f2bf(v.y); o.z = f2bf(v.z); o.w = f2bf(v.w);
    ((short4*)out)[j] = o;
}

// all 7 weight transposes in one launch (444 tiles of 64x64)
__global__ __launch_bounds__(256) void transpose_all(
    const float* __restrict__ Wq, const float* __restrict__ Wk, const float* __restrict__ Wv,
    const float* __restrict__ Wu, const float* __restrict__ Wn,
    const float* __restrict__ W1, const float* __restrict__ W2,
    short* __restrict__ WquT, short* __restrict__ WkT, short* __restrict__ WvT,
    short* __restrict__ WnT, short* __restrict__ W1T, short* __restrict__ W2T)
{
    __shared__ float tile[64][65];
    int b = blockIdx.x;
    const float* in; short* out; int R, C, local;
    if (b < 36)       { in = Wq; out = WquT;          R = 384;  C = 384;  local = b; }
    else if (b < 60)  { in = Wk; out = WkT;           R = 256;  C = 384;  local = b - 36; }
    else if (b < 84)  { in = Wv; out = WvT;           R = 256;  C = 384;  local = b - 60; }
    else if (b < 120) { in = Wu; out = WquT + 147456; R = 384;  C = 384;  local = b - 84; }
    else if (b < 156) { in = Wn; out = WnT;           R = 384;  C = 384;  local = b - 120; }
    else if (b < 300) { in = W1; out = W1T;           R = 384;  C = 1536; local = b - 156; }
    else              { in = W2; out = W2T;           R = 1536; C = 384;  local = b - 300; }
    const int nbx = C >> 6;
    const int r0 = (local / nbx) * 64, c0 = (local % nbx) * 64;
    const int lr = threadIdx.x >> 6, lc = threadIdx.x & 63;
#pragma unroll
    for (int i = 0; i < 16; ++i) {
        int r = lr * 16 + i;
        tile[r][lc] = in[(long long)(r0 + r) * C + c0 + lc];
    }
    __syncthreads();
#pragma unroll
    for (int i = 0; i < 16; ++i) {
        int r = lr * 16 + i;
        out[(long long)(c0 + r) * R + r0 + lc] = f2bf(tile[lc][r]);
    }
}

// fp32 [R,C] -> bf16 [C,R], per-batch strides (for score_c)
__global__ __launch_bounds__(256) void transpose_cast(
    const float* __restrict__ in, short* __restrict__ out,
    int R, int C, long long sIn, long long sOut)
{
    __shared__ float tile[64][65];
    const long long zi = (long long)blockIdx.z * sIn;
    const long long zo = (long long)blockIdx.z * sOut;
    const int r0 = blockIdx.y * 64, c0 = blockIdx.x * 64;
    const int lr = threadIdx.x >> 6, lc = threadIdx.x & 63;
#pragma unroll
    for (int i = 0; i < 16; ++i) {
        int r = lr * 16 + i;
        tile[r][lc] = in[zi + (long long)(r0 + r) * C + c0 + lc];
    }
    __syncthreads();
#pragma unroll
    for (int i = 0; i < 16; ++i) {
        int r = lr * 16 + i;
        out[zo + (long long)(c0 + r) * R + r0 + lc] = f2bf(tile[lc][r]);
    }
}

// blended dual softmax over rows of length 2048
__global__ __launch_bounds__(256) void softmax_blend(
    const short* __restrict__ attb, const short* __restrict__ mixb,
    const float* __restrict__ a1p,
    float* __restrict__ outF, short* __restrict__ outB)
{
    const int S = 2048;
    const long long row = blockIdx.x;
    const short* ar = attb + row * S;
    const short* mr = mixb + row * S;
    const int t = threadIdx.x;
    const int wave = t >> 6;

    bf16x8 a8 = *(const bf16x8*)&ar[t * 8];
    bf16x8 m8 = *(const bf16x8*)&mr[t * 8];
    float av[8], mv[8];
#pragma unroll
    for (int i = 0; i < 8; ++i) { av[i] = bf2f(a8[i]); mv[i] = bf2f(m8[i]); }

    float amax = av[0], mmax = mv[0];
#pragma unroll
    for (int i = 1; i < 8; ++i) { amax = fmaxf(amax, av[i]); mmax = fmaxf(mmax, mv[i]); }
#pragma unroll
    for (int o = 32; o; o >>= 1) {
        amax = fmaxf(amax, __shfl_xor(amax, o));
        mmax = fmaxf(mmax, __shfl_xor(mmax, o));
    }
    __shared__ float red[2][4];
    if ((t & 63) == 0) { red[0][wave] = amax; red[1][wave] = mmax; }
    __syncthreads();
    amax = fmaxf(fmaxf(red[0][0], red[0][1]), fmaxf(red[0][2], red[0][3]));
    mmax = fmaxf(fmaxf(red[1][0], red[1][1]), fmaxf(red[1][2], red[1][3]));

    float asum = 0.f, msum = 0.f;
#pragma unroll
    for (int i = 0; i < 8; ++i) {
        av[i] = __expf(av[i] - amax); asum += av[i];
        mv[i] = __expf(mv[i] - mmax); msum += mv[i];
    }
#pragma unroll
    for (int o = 32; o; o >>= 1) {
        asum += __shfl_xor(asum, o);
        msum += __shfl_xor(msum, o);
    }
    __shared__ float red2[2][4];
    if ((t & 63) == 0) { red2[0][wave] = asum; red2[1][wave] = msum; }
    __syncthreads();
    asum = red2[0][0] + red2[0][1] + red2[0][2] + red2[0][3];
    msum = red2[1][0] + red2[1][1] + red2[1][2] + red2[1][3];

    const float a1 = a1p[0];
    const float wm = a1 / msum;
    const float wa = (1.0f - a1) / asum;

    float o0[8];
    bf16x8 ob;
#pragma unroll
    for (int i = 0; i < 8; ++i) {
        float s = wm * mv[i] + wa * av[i];
        o0[i] = s;
        ob[i] = f2bf(s);
    }
    float4 f0, f1;
    f0.x = o0[0]; f0.y = o0[1]; f0.z = o0[2]; f0.w = o0[3];
    f1.x = o0[4]; f1.y = o0[5]; f1.z = o0[6]; f1.w = o0[7];
    *(float4*)&outF[row * S + t * 8] = f0;
    *(float4*)&outF[row * S + t * 8 + 4] = f1;
    *(bf16x8*)&outB[row * S + t * 8] = ob;
}

// LayerNorm over D=384 of (X + Yr); one wave per row, 4 rows/block
template<int WRITE_BF>
__global__ __launch_bounds__(256) void ln_kernel(
    const float* __restrict__ X, const float* __restrict__ Yr,
    const float* __restrict__ g, const float* __restrict__ be,
    float* __restrict__ outF, short* __restrict__ outB)
{
    const int Dm = 384;
    const int wave = threadIdx.x >> 6, lane = threadIdx.x & 63;
    const long long row = (long long)blockIdx.x * 4 + wave;
    const float* x = X + row * Dm;
    const float* y = Yr + row * Dm;
    float h[6];
    float s = 0.f, s2 = 0.f;
#pragma unroll
    for (int j = 0; j < 6; ++j) {
        int c = j * 64 + lane;
        h[j] = x[c] + y[c];
        s += h[j]; s2 += h[j] * h[j];
    }
#pragma unroll
    for (int o = 32; o; o >>= 1) { s += __shfl_xor(s, o); s2 += __shfl_xor(s2, o); }
    const float mean = s * (1.0f / 384.0f);
    const float var = s2 * (1.0f / 384.0f) - mean * mean;
    const float rstd = rsqrtf(var + 1e-5f);
#pragma unroll
    for (int j = 0; j < 6; ++j) {
        int c = j * 64 + lane;
        float v = (h[j] - mean) * rstd * g[c] + be[c];
        outF[row * Dm + c] = v;
        if (WRITE_BF) outB[row * Dm + c] = f2bf(v);
    }
}

extern "C" void kernel_launch(void* const* d_in, const int* in_sizes, int n_in,
                              void* d_out, int out_size, void* d_ws, size_t ws_size,
                              hipStream_t stream) {
    const float* tgt     = (const float*)d_in[0];
    const float* memory  = (const float*)d_in[1];
    const float* a1      = (const float*)d_in[2];
    const float* score_c = (const float*)d_in[3];
    const float* out_c   = (const float*)d_in[4];
    const float* Wq = (const float*)d_in[5];  const float* bq = (const float*)d_in[6];
    const float* Wk = (const float*)d_in[7];  const float* bk = (const float*)d_in[8];
    const float* Wv = (const float*)d_in[9];  const float* bv = (const float*)d_in[10];
    const float* Wu = (const float*)d_in[11]; const float* bu = (const float*)d_in[12];
    const float* Wn = (const float*)d_in[13]; const float* bn = (const float*)d_in[14];
    const float* W1 = (const float*)d_in[15]; const float* b1 = (const float*)d_in[16];
    const float* W2 = (const float*)d_in[17]; const float* b2 = (const float*)d_in[18];
    const float* g1 = (const float*)d_in[19]; const float* be1 = (const float*)d_in[20];
    const float* g2 = (const float*)d_in[21]; const float* be2 = (const float*)d_in[22];

    const long long BT = 16384;            // B*T
    const long long S2 = 2048LL * 2048;    // per-batch score matrix elems
    const long long PB = 2048LL * 384;     // per-batch [2048,384] panel elems
    char* ws = (char*)d_ws;
    size_t off = 0;
    auto A_ = [&](size_t b) { size_t r = off; off += (b + 255) & ~(size_t)255; return r; };

    const size_t oTgtB  = A_(BT * 384 * 2);
    const size_t oMemB  = A_(BT * 256 * 2);
    const size_t oOutcB = A_(BT * 384 * 2);
    const size_t oWquT  = A_(768 * 384 * 2);
    const size_t oWnT   = A_(384 * 384 * 2);
    const size_t oWkT   = A_(384 * 256 * 2);
    const size_t oWvT   = A_(384 * 256 * 2);
    const size_t oW1T   = A_(1536 * 384 * 2);
    const size_t oW2T   = A_(384 * 1536 * 2);
    const size_t oQUb   = A_(768 * 4);
    const size_t oQU    = A_(16 * PB * 2);  // qu packed [16384, 768]
    const size_t oKP    = A_(16 * PB * 2);  // k (0-7), Pt (8-15)
    const size_t oVT    = A_(8LL * 384 * 2048 * 2);
    const size_t oJ     = A_(8 * S2 * 2);   // score_bf (blend output)
    const size_t oKr    = A_(8 * S2 * 2);   // scoreCt bf16; later z fp32
    const size_t oAM    = A_(16 * S2 * 2);  // knoT early; att (0-7) + mixed (8-15); later h_bf / ff_f
    const size_t oX     = A_(BT * 384 * 4);
    const size_t oXB    = A_(BT * 384 * 2);

    short* tgt_bf  = (short*)(ws + oTgtB);
    short* mem_bf  = (short*)(ws + oMemB);
    short* outc_bf = (short*)(ws + oOutcB);
    short* WquT = (short*)(ws + oWquT);
    short* WnT  = (short*)(ws + oWnT);
    short* WkT  = (short*)(ws + oWkT);
    short* WvT  = (short*)(ws + oWvT);
    short* W1T  = (short*)(ws + oW1T);
    short* W2T  = (short*)(ws + oW2T);
    float* qu_bias = (float*)(ws + oQUb);
    short* qu_bf  = (short*)(ws + oQU);
    short* k_bf   = (short*)(ws + oKP);
    short* Pt_bf  = k_bf + 8 * PB;
    short* vT_bf  = (short*)(ws + oVT);
    short* score_bf = (short*)(ws + oJ);
    short* scoreCt  = (short*)(ws + oKr);
    float* z_f      = (float*)(ws + oKr);   // alias (scoreCt dead after Pt GEMM)
    short* knoT_bf  = (short*)(ws + oAM);   // alias: dead before att written
    short* att_bf   = (short*)(ws + oAM);
    short* mix_bf   = att_bf + 8 * S2;
    short* h_bf     = (short*)(ws + oAM);               // alias (att dead after blend)
    float* ff_f     = (float*)(ws + oAM + 8 * S2 * 2);  // alias (mixed dead after blend)
    float* x_f  = (float*)(ws + oX);
    short* x_bf = (short*)(ws + oXB);

    float* outMain = (float*)d_out;
    float* outScore = (float*)d_out + 6291456;   // B*T*D elements

    const float SC = 0.05103103630798288f;  // 1/sqrt(384)
    dim3 blk(256);

    // fused prologue
    cast_all<<<16385, blk, 0, stream>>>(tgt, memory, out_c, bq, bu,
                                        tgt_bf, mem_bf, outc_bf, qu_bias);
    transpose_all<<<444, blk, 0, stream>>>(Wq, Wk, Wv, Wu, Wn, W1, W2,
                                           WquT, WkT, WvT, WnT, W1T, W2T);
    transpose_cast<<<dim3(32, 32, 8), blk, 0, stream>>>(score_c, scoreCt, 2048, 2048, S2, S2);

    // q|unknow packed projection: [16384, 768]
    gemm128p<1, 1, 0><<<dim3(6, 128, 1), blk, 0, stream>>>(
        tgt_bf, WquT, qu_bf, qu_bias, 384, 384, 384, 768, 0, 0, 0, 1.0f);
    // k projection
    gemm128p<1, 1, 0><<<dim3(3, 128, 1), blk, 0, stream>>>(
        mem_bf, WkT, k_bf, bk, 256, 256, 256, 384, 0, 0, 0, 1.0f);
    // vT (z 0-7) + knoT (z 8-15) merged
    gemm128pz<<<dim3(16, 3, 16), blk, 0, stream>>>(
        WvT, mem_bf, vT_bf, bv, 256, 256, 256, 2048, 2048LL * 256, PB,
        WnT, outc_bf, knoT_bf, bn, 384, 384, 384, 2048, PB, PB);
    // Pt[s,d] = sum_c score_c[c,s] * know[c,d]
    gemm128p<1, 0, 0><<<dim3(3, 16, 8), blk, 0, stream>>>(
        scoreCt, knoT_bf, Pt_bf, nullptr, 2048, 2048, 2048, 384, S2, PB, PB, 1.0f);
    // fused att (accA: q,k) + mixed (accB: unk, Pt)
    gemm128dd<<<dim3(16, 16, 8), blk, 0, stream>>>(
        qu_bf, k_bf, att_bf, 384, 768, 384, 2048,
        2048LL * 768, PB, S2, 384, 8 * PB, 8 * S2, SC);
    // score = a1*softmax(mixed) + (1-a1)*softmax(att)
    softmax_blend<<<16384, blk, 0, stream>>>(att_bf, mix_bf, a1, outScore, score_bf);
    // z = score @ v
    gemm128p<0, 0, 0><<<dim3(3, 16, 8), blk, 0, stream>>>(
        score_bf, vT_bf, z_f, nullptr, 2048, 2048, 2048, 384, S2, PB, PB, 1.0f);
    // x = LN(tgt + z)
    ln_kernel<1><<<4096, blk, 0, stream>>>(tgt, z_f, g1, be1, x_f, x_bf);
    // FFN
    gemm128p<1, 1, 1><<<dim3(12, 128, 1), blk, 0, stream>>>(
        x_bf, W1T, h_bf, b1, 384, 384, 384, 1536, 0, 0, 0, 1.0f);
    gemm128p<0, 1, 0><<<dim3(3, 128, 1), blk, 0, stream>>>(
        h_bf, W2T, ff_f, b2, 1536, 1536, 1536, 384, 0, 0, 0, 1.0f);
    // out = LN(x + ff)
    ln_kernel<0><<<4096, blk, 0, stream>>>(x_f, ff_f, g2, be2, outMain, nullptr);
}

// Round 7
// 456.269 us; speedup vs baseline: 1.4669x; 1.0090x over previous
//
#include <hip/hip_runtime.h>
#include <stdint.h>

typedef __attribute__((ext_vector_type(8))) short bf16x8;
typedef __attribute__((ext_vector_type(4))) float f32x4;

__device__ __forceinline__ short f2bf(float f) {
    union { float f; unsigned u; } v; v.f = f;
    unsigned r = v.u + 0x7fffu + ((v.u >> 16) & 1u);
    return (short)(r >> 16);
}
__device__ __forceinline__ float bf2f(short s) {
    union { unsigned u; float f; } v;
    v.u = ((unsigned)(unsigned short)s) << 16;
    return v.f;
}

__device__ __forceinline__ void gld16(const void* g, void* l) {
    auto gp = reinterpret_cast<const __attribute__((address_space(1))) unsigned int*>(
        reinterpret_cast<uintptr_t>(g));
    auto lp = reinterpret_cast<__attribute__((address_space(3))) unsigned int*>(
        reinterpret_cast<uintptr_t>(l));
    __builtin_amdgcn_global_load_lds(gp, lp, 16, 0, 0);
}

// ---------------------------------------------------------------------------
// gemm128r: 128x128 NT GEMM, BK=32, 4 waves, 3-buffer LDS ring (48 KiB ->
// 3 blocks/CU). One barrier + one counted vmcnt per K-tile; stage distance 2
// (tile kt stages kt+2; boundary waits vmcnt(4): the drained loads were
// issued 2 tiles earlier -> full latency cover, queue never drains).
// Swizzle: 64B rows = 4 segs; seg ^= (r&3)^((r>>2)&3) (involution), source
// pre-swizzled, read swizzled; per-8-lane cycle groups hit all 32 banks once.
// C[m,n] = scale*(sum_k A[m,k]B[n,k]) (+bias)(+relu).
// Batch addressing: z = blockIdx.z; A += (z&7)*sA + (z>>3)*dA (same B,C) so
// one launch can cover two operand sets at z=8..15.
// M%128==0, N%128==0, K%64==0 (NT>=2), nwg%8==0.
// ---------------------------------------------------------------------------
template<int OUTBF, int BIASMODE /*0 none,1 col,2 row*/, int DORELU>
__global__ __launch_bounds__(256, 3) void gemm128r(
    const short* __restrict__ Ag, const short* __restrict__ Bg,
    void* __restrict__ Cg, const float* __restrict__ bias,
    int K, int lda, int ldb, int ldc,
    long long sA, long long sB, long long sC,
    long long dA, long long dB, long long dC, float scale)
{
    __shared__ short lds[3 * 8192];   // per buf: A[128][32] (4096 sh) | B[128][32]
    const int t = threadIdx.x;
    const int lane = t & 63;
    const int wave = t >> 6;
    const int wm = wave >> 1, wn = wave & 1;

    const int gx = gridDim.x, gy = gridDim.y;
    const int nwg = gx * gy * gridDim.z;
    int id = blockIdx.x + gx * (blockIdx.y + gy * blockIdx.z);
    id = (id & 7) * (nwg >> 3) + (id >> 3);
    const int bx = id % gx;
    const int by = (id / gx) % gy;
    const int bz = id / (gx * gy);
    const int zlo = bz & 7, zhi = bz >> 3;

    const long long row0 = (long long)by * 128;
    const long long col0 = (long long)bx * 128;
    const int NT = K >> 5;

    // staging: thread t -> A rows (t>>2) and 64+(t>>2), 16B seg (t&3).
    // linear LDS dest = t*8 shorts (+2048 for upper rows); source col
    // pre-swizzled with the involution so swizzled reads see correct data.
    const int gk = ((t & 3) ^ ((t >> 2) & 3) ^ ((t >> 4) & 3)) * 8;
    const short* Asrc = Ag + zlo * sA + zhi * dA + (row0 + (t >> 2)) * (long long)lda + gk;
    const short* Bsrc = Bg + zlo * sB + zhi * dB + (col0 + (t >> 2)) * (long long)ldb + gk;

    const int frow = lane & 15;
    const int fcol = ((lane >> 4) ^ (frow & 3) ^ ((frow >> 2) & 3)) * 8;

    f32x4 acc[4][4] = {};

#define STG(BUF, KC) do { \
        gld16(Asrc + (KC), &lds[(BUF) * 8192 + t * 8]); \
        gld16(Asrc + (KC) + 64LL * lda, &lds[(BUF) * 8192 + 2048 + t * 8]); \
        gld16(Bsrc + (KC), &lds[(BUF) * 8192 + 4096 + t * 8]); \
        gld16(Bsrc + (KC) + 64LL * ldb, &lds[(BUF) * 8192 + 6144 + t * 8]); } while (0)

    // prologue: stage tiles 0 and 1; wait tile 0 (leave tile 1's 4 in flight)
    STG(0, 0);
    STG(1, 32);
    asm volatile("s_waitcnt vmcnt(4)\ns_barrier" ::: "memory");

    for (int kt = 0; kt < NT; ++kt) {
        const int rb = (kt % 3) * 8192;
        bf16x8 av[4], bv[4];
#pragma unroll
        for (int m = 0; m < 4; ++m)
            av[m] = *(const bf16x8*)&lds[rb + (wm * 64 + m * 16 + frow) * 32 + fcol];
#pragma unroll
        for (int n = 0; n < 4; ++n)
            bv[n] = *(const bf16x8*)&lds[rb + 4096 + (wn * 64 + n * 16 + frow) * 32 + fcol];
        if (kt + 2 < NT) STG((kt + 2) % 3, (long long)(kt + 2) * 32);
        __builtin_amdgcn_s_setprio(1);
#pragma unroll
        for (int m = 0; m < 4; ++m)
#pragma unroll
            for (int n = 0; n < 4; ++n)
                acc[m][n] = __builtin_amdgcn_mfma_f32_16x16x32_bf16(av[m], bv[n], acc[m][n], 0, 0, 0);
        __builtin_amdgcn_s_setprio(0);
        if (kt + 1 < NT) {
            if (kt + 2 < NT) asm volatile("s_waitcnt vmcnt(4)\ns_barrier" ::: "memory");
            else             asm volatile("s_waitcnt vmcnt(0)\ns_barrier" ::: "memory");
        }
    }
#undef STG

    const int crow = (lane >> 4) * 4;
    const int ccol = lane & 15;
    const long long cz = zlo * sC + zhi * dC;
#pragma unroll
    for (int m = 0; m < 4; ++m)
#pragma unroll
        for (int n = 0; n < 4; ++n)
#pragma unroll
            for (int i = 0; i < 4; ++i) {
                long long r = row0 + wm * 64 + m * 16 + crow + i;
                long long c = col0 + wn * 64 + n * 16 + ccol;
                float v = acc[m][n][i] * scale;
                if (BIASMODE == 1) v += bias[c];
                if (BIASMODE == 2) v += bias[r];
                if (DORELU) v = fmaxf(v, 0.0f);
                long long idx = cz + r * (long long)ldc + c;
                if (OUTBF) ((short*)Cg)[idx] = f2bf(v);
                else ((float*)Cg)[idx] = v;
            }
}

// ---------------------------------------------------------------------------
// gemm128pz: dual-parameter 2-phase engine (verified round 6), z<8 -> set 1
// (vT), z>=8 -> set 2 (knoT). Both: C = A @ B^T + rowbias, A = weight.
// ---------------------------------------------------------------------------
#define RD_A(RB, M, KS) (*(const bf16x8*)&lds[(RB) + (wm * 64 + (M) * 16 + frow) * 64 + \
        ((((KS) << 2) | fq) ^ (frow & 7)) * 8])
#define RD_B(RB, Nn, KS) (*(const bf16x8*)&lds[(RB) + 8192 + (wn * 64 + (Nn) * 16 + frow) * 64 + \
        ((((KS) << 2) | fq) ^ (frow & 7)) * 8])

__global__ __launch_bounds__(256, 2) void gemm128pz(
    const short* __restrict__ A1, const short* __restrict__ B1, short* __restrict__ C1,
    const float* __restrict__ bias1, int K1, int lda1, int ldb1, int ldc1,
    long long sB1, long long sC1,
    const short* __restrict__ A2, const short* __restrict__ B2, short* __restrict__ C2,
    const float* __restrict__ bias2, int K2, int lda2, int ldb2, int ldc2,
    long long sB2, long long sC2)
{
    __shared__ short lds[2 * 16384];
    const int t = threadIdx.x;
    const int lane = t & 63;
    const int wave = t >> 6;
    const int wm = wave >> 1, wn = wave & 1;

    const int gx = gridDim.x, gy = gridDim.y;
    const int nwg = gx * gy * gridDim.z;
    int id = blockIdx.x + gx * (blockIdx.y + gy * blockIdx.z);
    id = (id & 7) * (nwg >> 3) + (id >> 3);
    const int bx = id % gx;
    const int by = (id / gx) % gy;
    const int bz = id / (gx * gy);

    const bool sel = bz >= 8;
    const int zz = bz & 7;
    const short* Ag = sel ? A2 : A1;
    const short* Bg = sel ? B2 : B1;
    short* Cg = sel ? C2 : C1;
    const float* bias = sel ? bias2 : bias1;
    const int K = sel ? K2 : K1;
    const int lda = sel ? lda2 : lda1;
    const int ldb = sel ? ldb2 : ldb1;
    const int ldc = sel ? ldc2 : ldc1;
    const long long sB = sel ? sB2 : sB1;
    const long long sC = sel ? sC2 : sC1;

    const long long row0 = (long long)by * 128;
    const long long col0 = (long long)bx * 128;
    const int NT = K >> 6;

    const int srow = t >> 3;
    const int gk = ((t & 7) ^ (srow & 7)) * 8;
    const short* Asrc = Ag + (row0 + srow) * (long long)lda + gk;
    const short* Bsrc = Bg + (long long)zz * sB + (col0 + srow) * (long long)ldb + gk;

    const int frow = lane & 15;
    const int fq = lane >> 4;

    f32x4 acc[4][4] = {};

#define STAGE_A(WB, KC) do { _Pragma("unroll") \
        for (int r = 0; r < 4; ++r) \
            gld16(Asrc + (KC) + (long long)r * 32 * lda, &lds[(WB) + t * 8 + r * 2048]); } while (0)
#define STAGE_B(WB, KC) do { _Pragma("unroll") \
        for (int r = 0; r < 4; ++r) \
            gld16(Bsrc + (KC) + (long long)r * 32 * ldb, &lds[(WB) + 8192 + t * 8 + r * 2048]); } while (0)

    STAGE_A(0, 0);
    STAGE_B(0, 0);
    asm volatile("s_waitcnt vmcnt(0)\ns_barrier" ::: "memory");

    for (int kt = 0; kt < NT; ++kt) {
        const int rb = (kt & 1) << 14;
        const int wb = ((kt + 1) & 1) << 14;
        const bool st = (kt + 1) < NT;
        const long long kc = (long long)(kt + 1) << 6;

        bf16x8 av[4], bv[4];

#pragma unroll
        for (int m = 0; m < 4; ++m) av[m] = RD_A(rb, m, 0);
#pragma unroll
        for (int n = 0; n < 4; ++n) bv[n] = RD_B(rb, n, 0);
        if (st) STAGE_A(wb, kc);
        asm volatile("s_barrier" ::: "memory");
        __builtin_amdgcn_s_setprio(1);
#pragma unroll
        for (int m = 0; m < 4; ++m)
#pragma unroll
            for (int n = 0; n < 4; ++n)
                acc[m][n] = __builtin_amdgcn_mfma_f32_16x16x32_bf16(av[m], bv[n], acc[m][n], 0, 0, 0);
        __builtin_amdgcn_s_setprio(0);
        asm volatile("s_barrier" ::: "memory");

#pragma unroll
        for (int m = 0; m < 4; ++m) av[m] = RD_A(rb, m, 1);
#pragma unroll
        for (int n = 0; n < 4; ++n) bv[n] = RD_B(rb, n, 1);
        if (st) STAGE_B(wb, kc);
        asm volatile("s_barrier" ::: "memory");
        __builtin_amdgcn_s_setprio(1);
#pragma unroll
        for (int m = 0; m < 4; ++m)
#pragma unroll
            for (int n = 0; n < 4; ++n)
                acc[m][n] = __builtin_amdgcn_mfma_f32_16x16x32_bf16(av[m], bv[n], acc[m][n], 0, 0, 0);
        __builtin_amdgcn_s_setprio(0);
        if (st) asm volatile("s_waitcnt vmcnt(0)\ns_barrier" ::: "memory");
        else    asm volatile("s_barrier" ::: "memory");
    }
#undef STAGE_A
#undef STAGE_B

    const int crow = (lane >> 4) * 4;
    const int ccol = lane & 15;
    const long long cz = (long long)zz * sC;
#pragma unroll
    for (int m = 0; m < 4; ++m)
#pragma unroll
        for (int n = 0; n < 4; ++n)
#pragma unroll
            for (int i = 0; i < 4; ++i) {
                long long r = row0 + wm * 64 + m * 16 + crow + i;
                long long c = col0 + wn * 64 + n * 16 + ccol;
                float v = acc[m][n][i] + bias[r];
                Cg[cz + r * (long long)ldc + c] = f2bf(v);
            }
}
#undef RD_A
#undef RD_B

// fused casts: tgt, memory, out_c -> bf16; concat bq|bu -> qu_bias (fp32)
__global__ __launch_bounds__(256) void cast_all(
    const float* __restrict__ tgt, const float* __restrict__ mem, const float* __restrict__ outc,
    const float* __restrict__ bq, const float* __restrict__ bu,
    short* __restrict__ tgtb, short* __restrict__ memb, short* __restrict__ outcb,
    float* __restrict__ qubias)
{
    const long long R1 = 1572864;            // tgt f4
    const long long R2 = R1 + 1048576;       // memory f4
    const long long R3 = R2 + 1572864;       // out_c f4
    const long long R4 = R3 + 192;           // bias f4
    long long i = (long long)blockIdx.x * 256 + threadIdx.x;
    const float* in; short* out; long long j;
    if (i < R1) { in = tgt; out = tgtb; j = i; }
    else if (i < R2) { in = mem; out = memb; j = i - R1; }
    else if (i < R3) { in = outc; out = outcb; j = i - R2; }
    else if (i < R4) {
        j = i - R3;
        ((float4*)qubias)[j] = (j < 96) ? ((const float4*)bq)[j] : ((const float4*)bu)[j - 96];
        return;
    } else return;
    float4 v = ((const float4*)in)[j];
    short4 o;
    o.x = f2bf(v.x); o.y = f2bf(v.y); o.z = f2bf(v.z); o.w = f2bf(v.w);
    ((short4*)out)[j] = o;
}

// all 7 weight transposes in one launch (444 tiles of 64x64)
__global__ __launch_bounds__(256) void transpose_all(
    const float* __restrict__ Wq, const float* __restrict__ Wk, const float* __restrict__ Wv,
    const float* __restrict__ Wu, const float* __restrict__ Wn,
    const float* __restrict__ W1, const float* __restrict__ W2,
    short* __restrict__ WquT, short* __restrict__ WkT, short* __restrict__ WvT,
    short* __restrict__ WnT, short* __restrict__ W1T, short* __restrict__ W2T)
{
    __shared__ float tile[64][65];
    int b = blockIdx.x;
    const float* in; short* out; int R, C, local;
    if (b < 36)       { in = Wq; out = WquT;          R = 384;  C = 384;  local = b; }
    else if (b < 60)  { in = Wk; out = WkT;           R = 256;  C = 384;  local = b - 36; }
    else if (b < 84)  { in = Wv; out = WvT;           R = 256;  C = 384;  local = b - 60; }
    else if (b < 120) { in = Wu; out = WquT + 147456; R = 384;  C = 384;  local = b - 84; }
    else if (b < 156) { in = Wn; out = WnT;           R = 384;  C = 384;  local = b - 120; }
    else if (b < 300) { in = W1; out = W1T;           R = 384;  C = 1536; local = b - 156; }
    else              { in = W2; out = W2T;           R = 1536; C = 384;  local = b - 300; }
    const int nbx = C >> 6;
    const int r0 = (local / nbx) * 64, c0 = (local % nbx) * 64;
    const int lr = threadIdx.x >> 6, lc = threadIdx.x & 63;
#pragma unroll
    for (int i = 0; i < 16; ++i) {
        int r = lr * 16 + i;
        tile[r][lc] = in[(long long)(r0 + r) * C + c0 + lc];
    }
    __syncthreads();
#pragma unroll
    for (int i = 0; i < 16; ++i) {
        int r = lr * 16 + i;
        out[(long long)(c0 + r) * R + r0 + lc] = f2bf(tile[lc][r]);
    }
}

// fp32 [R,C] -> bf16 [C,R], per-batch strides (for score_c)
__global__ __launch_bounds__(256) void transpose_cast(
    const float* __restrict__ in, short* __restrict__ out,
    int R, int C, long long sIn, long long sOut)
{
    __shared__ float tile[64][65];
    const long long zi = (long long)blockIdx.z * sIn;
    const long long zo = (long long)blockIdx.z * sOut;
    const int r0 = blockIdx.y * 64, c0 = blockIdx.x * 64;
    const int lr = threadIdx.x >> 6, lc = threadIdx.x & 63;
#pragma unroll
    for (int i = 0; i < 16; ++i) {
        int r = lr * 16 + i;
        tile[r][lc] = in[zi + (long long)(r0 + r) * C + c0 + lc];
    }
    __syncthreads();
#pragma unroll
    for (int i = 0; i < 16; ++i) {
        int r = lr * 16 + i;
        out[zo + (long long)(c0 + r) * R + r0 + lc] = f2bf(tile[lc][r]);
    }
}

// blended dual softmax over rows of length 2048
__global__ __launch_bounds__(256) void softmax_blend(
    const short* __restrict__ attb, const short* __restrict__ mixb,
    const float* __restrict__ a1p,
    float* __restrict__ outF, short* __restrict__ outB)
{
    const int S = 2048;
    const long long row = blockIdx.x;
    const short* ar = attb + row * S;
    const short* mr = mixb + row * S;
    const int t = threadIdx.x;
    const int wave = t >> 6;

    bf16x8 a8 = *(const bf16x8*)&ar[t * 8];
    bf16x8 m8 = *(const bf16x8*)&mr[t * 8];
    float av[8], mv[8];
#pragma unroll
    for (int i = 0; i < 8; ++i) { av[i] = bf2f(a8[i]); mv[i] = bf2f(m8[i]); }

    float amax = av[0], mmax = mv[0];
#pragma unroll
    for (int i = 1; i < 8; ++i) { amax = fmaxf(amax, av[i]); mmax = fmaxf(mmax, mv[i]); }
#pragma unroll
    for (int o = 32; o; o >>= 1) {
        amax = fmaxf(amax, __shfl_xor(amax, o));
        mmax = fmaxf(mmax, __shfl_xor(mmax, o));
    }
    __shared__ float red[2][4];
    if ((t & 63) == 0) { red[0][wave] = amax; red[1][wave] = mmax; }
    __syncthreads();
    amax = fmaxf(fmaxf(red[0][0], red[0][1]), fmaxf(red[0][2], red[0][3]));
    mmax = fmaxf(fmaxf(red[1][0], red[1][1]), fmaxf(red[1][2], red[1][3]));

    float asum = 0.f, msum = 0.f;
#pragma unroll
    for (int i = 0; i < 8; ++i) {
        av[i] = __expf(av[i] - amax); asum += av[i];
        mv[i] = __expf(mv[i] - mmax); msum += mv[i];
    }
#pragma unroll
    for (int o = 32; o; o >>= 1) {
        asum += __shfl_xor(asum, o);
        msum += __shfl_xor(msum, o);
    }
    __shared__ float red2[2][4];
    if ((t & 63) == 0) { red2[0][wave] = asum; red2[1][wave] = msum; }
    __syncthreads();
    asum = red2[0][0] + red2[0][1] + red2[0][2] + red2[0][3];
    msum = red2[1][0] + red2[1][1] + red2[1][2] + red2[1][3];

    const float a1 = a1p[0];
    const float wm = a1 / msum;
    const float wa = (1.0f - a1) / asum;

    float o0[8];
    bf16x8 ob;
#pragma unroll
    for (int i = 0; i < 8; ++i) {
        float s = wm * mv[i] + wa * av[i];
        o0[i] = s;
        ob[i] = f2bf(s);
    }
    float4 f0, f1;
    f0.x = o0[0]; f0.y = o0[1]; f0.z = o0[2]; f0.w = o0[3];
    f1.x = o0[4]; f1.y = o0[5]; f1.z = o0[6]; f1.w = o0[7];
    *(float4*)&outF[row * S + t * 8] = f0;
    *(float4*)&outF[row * S + t * 8 + 4] = f1;
    *(bf16x8*)&outB[row * S + t * 8] = ob;
}

// LayerNorm over D=384 of (X + Yr); one wave per row, 4 rows/block
template<int WRITE_BF>
__global__ __launch_bounds__(256) void ln_kernel(
    const float* __restrict__ X, const float* __restrict__ Yr,
    const float* __restrict__ g, const float* __restrict__ be,
    float* __restrict__ outF, short* __restrict__ outB)
{
    const int Dm = 384;
    const int wave = threadIdx.x >> 6, lane = threadIdx.x & 63;
    const long long row = (long long)blockIdx.x * 4 + wave;
    const float* x = X + row * Dm;
    const float* y = Yr + row * Dm;
    float h[6];
    float s = 0.f, s2 = 0.f;
#pragma unroll
    for (int j = 0; j < 6; ++j) {
        int c = j * 64 + lane;
        h[j] = x[c] + y[c];
        s += h[j]; s2 += h[j] * h[j];
    }
#pragma unroll
    for (int o = 32; o; o >>= 1) { s += __shfl_xor(s, o); s2 += __shfl_xor(s2, o); }
    const float mean = s * (1.0f / 384.0f);
    const float var = s2 * (1.0f / 384.0f) - mean * mean;
    const float rstd = rsqrtf(var + 1e-5f);
#pragma unroll
    for (int j = 0; j < 6; ++j) {
        int c = j * 64 + lane;
        float v = (h[j] - mean) * rstd * g[c] + be[c];
        outF[row * Dm + c] = v;
        if (WRITE_BF) outB[row * Dm + c] = f2bf(v);
    }
}

extern "C" void kernel_launch(void* const* d_in, const int* in_sizes, int n_in,
                              void* d_out, int out_size, void* d_ws, size_t ws_size,
                              hipStream_t stream) {
    const float* tgt     = (const float*)d_in[0];
    const float* memory  = (const float*)d_in[1];
    const float* a1      = (const float*)d_in[2];
    const float* score_c = (const float*)d_in[3];
    const float* out_c   = (const float*)d_in[4];
    const float* Wq = (const float*)d_in[5];  const float* bq = (const float*)d_in[6];
    const float* Wk = (const float*)d_in[7];  const float* bk = (const float*)d_in[8];
    const float* Wv = (const float*)d_in[9];  const float* bv = (const float*)d_in[10];
    const float* Wu = (const float*)d_in[11]; const float* bu = (const float*)d_in[12];
    const float* Wn = (const float*)d_in[13]; const float* bn = (const float*)d_in[14];
    const float* W1 = (const float*)d_in[15]; const float* b1 = (const float*)d_in[16];
    const float* W2 = (const float*)d_in[17]; const float* b2 = (const float*)d_in[18];
    const float* g1 = (const float*)d_in[19]; const float* be1 = (const float*)d_in[20];
    const float* g2 = (const float*)d_in[21]; const float* be2 = (const float*)d_in[22];

    const long long BT = 16384;            // B*T
    const long long S2 = 2048LL * 2048;    // per-batch score matrix elems
    const long long PB = 2048LL * 384;     // per-batch [2048,384] panel elems
    char* ws = (char*)d_ws;
    size_t off = 0;
    auto A_ = [&](size_t b) { size_t r = off; off += (b + 255) & ~(size_t)255; return r; };

    const size_t oTgtB  = A_(BT * 384 * 2);
    const size_t oMemB  = A_(BT * 256 * 2);
    const size_t oOutcB = A_(BT * 384 * 2);
    const size_t oWquT  = A_(768 * 384 * 2);
    const size_t oWnT   = A_(384 * 384 * 2);
    const size_t oWkT   = A_(384 * 256 * 2);
    const size_t oWvT   = A_(384 * 256 * 2);
    const size_t oW1T   = A_(1536 * 384 * 2);
    const size_t oW2T   = A_(384 * 1536 * 2);
    const size_t oQUb   = A_(768 * 4);
    const size_t oQU    = A_(16 * PB * 2);  // qu packed [16384, 768]
    const size_t oKP    = A_(16 * PB * 2);  // k (0-7), Pt (8-15)
    const size_t oVT    = A_(8LL * 384 * 2048 * 2);
    const size_t oJ     = A_(8 * S2 * 2);   // score_bf (blend output)
    const size_t oKr    = A_(8 * S2 * 2);   // scoreCt bf16; later z fp32
    const size_t oAM    = A_(16 * S2 * 2);  // knoT early; att (0-7) + mixed (8-15); later h_bf / ff_f
    const size_t oX     = A_(BT * 384 * 4);
    const size_t oXB    = A_(BT * 384 * 2);

    short* tgt_bf  = (short*)(ws + oTgtB);
    short* mem_bf  = (short*)(ws + oMemB);
    short* outc_bf = (short*)(ws + oOutcB);
    short* WquT = (short*)(ws + oWquT);
    short* WnT  = (short*)(ws + oWnT);
    short* WkT  = (short*)(ws + oWkT);
    short* WvT  = (short*)(ws + oWvT);
    short* W1T  = (short*)(ws + oW1T);
    short* W2T  = (short*)(ws + oW2T);
    float* qu_bias = (float*)(ws + oQUb);
    short* qu_bf  = (short*)(ws + oQU);
    short* k_bf   = (short*)(ws + oKP);
    short* Pt_bf  = k_bf + 8 * PB;
    short* vT_bf  = (short*)(ws + oVT);
    short* score_bf = (short*)(ws + oJ);
    short* scoreCt  = (short*)(ws + oKr);
    float* z_f      = (float*)(ws + oKr);   // alias (scoreCt dead after Pt GEMM)
    short* knoT_bf  = (short*)(ws + oAM);   // alias: dead before att written
    short* att_bf   = (short*)(ws + oAM);
    short* mix_bf   = att_bf + 8 * S2;
    short* h_bf     = (short*)(ws + oAM);               // alias (att dead after blend)
    float* ff_f     = (float*)(ws + oAM + 8 * S2 * 2);  // alias (mixed dead after blend)
    float* x_f  = (float*)(ws + oX);
    short* x_bf = (short*)(ws + oXB);

    float* outMain = (float*)d_out;
    float* outScore = (float*)d_out + 6291456;   // B*T*D elements

    const float SC = 0.05103103630798288f;  // 1/sqrt(384)
    dim3 blk(256);

    // fused prologue
    cast_all<<<16385, blk, 0, stream>>>(tgt, memory, out_c, bq, bu,
                                        tgt_bf, mem_bf, outc_bf, qu_bias);
    transpose_all<<<444, blk, 0, stream>>>(Wq, Wk, Wv, Wu, Wn, W1, W2,
                                           WquT, WkT, WvT, WnT, W1T, W2T);
    transpose_cast<<<dim3(32, 32, 8), blk, 0, stream>>>(score_c, scoreCt, 2048, 2048, S2, S2);

    // q|unknow packed projection: [16384, 768]
    gemm128r<1, 1, 0><<<dim3(6, 128, 1), blk, 0, stream>>>(
        tgt_bf, WquT, qu_bf, qu_bias, 384, 384, 384, 768, 0, 0, 0, 0, 0, 0, 1.0f);
    // k projection
    gemm128r<1, 1, 0><<<dim3(3, 128, 1), blk, 0, stream>>>(
        mem_bf, WkT, k_bf, bk, 256, 256, 256, 384, 0, 0, 0, 0, 0, 0, 1.0f);
    // vT (z 0-7) + knoT (z 8-15) merged
    gemm128pz<<<dim3(16, 3, 16), blk, 0, stream>>>(
        WvT, mem_bf, vT_bf, bv, 256, 256, 256, 2048, 2048LL * 256, PB,
        WnT, outc_bf, knoT_bf, bn, 384, 384, 384, 2048, PB, PB);
    // Pt[s,d] = sum_c score_c[c,s] * know[c,d]
    gemm128r<1, 0, 0><<<dim3(3, 16, 8), blk, 0, stream>>>(
        scoreCt, knoT_bf, Pt_bf, nullptr, 2048, 2048, 2048, 384,
        S2, PB, PB, 0, 0, 0, 1.0f);
    // att (z 0-7: q x k) + mixed (z 8-15: unk x Pt) in one launch via dA/dB/dC
    gemm128r<1, 0, 0><<<dim3(16, 16, 16), blk, 0, stream>>>(
        qu_bf, k_bf, att_bf, nullptr, 384, 768, 384, 2048,
        2048LL * 768, PB, S2, 384, 8 * PB, 8 * S2, SC);
    // score = a1*softmax(mixed) + (1-a1)*softmax(att)
    softmax_blend<<<16384, blk, 0, stream>>>(att_bf, mix_bf, a1, outScore, score_bf);
    // z = score @ v
    gemm128r<0, 0, 0><<<dim3(3, 16, 8), blk, 0, stream>>>(
        score_bf, vT_bf, z_f, nullptr, 2048, 2048, 2048, 384,
        S2, PB, PB, 0, 0, 0, 1.0f);
    // x = LN(tgt + z)
    ln_kernel<1><<<4096, blk, 0, stream>>>(tgt, z_f, g1, be1, x_f, x_bf);
    // FFN
    gemm128r<1, 1, 1><<<dim3(12, 128, 1), blk, 0, stream>>>(
        x_bf, W1T, h_bf, b1, 384, 384, 384, 1536, 0, 0, 0, 0, 0, 0, 1.0f);
    gemm128r<0, 1, 0><<<dim3(3, 128, 1), blk, 0, stream>>>(
        h_bf, W2T, ff_f, b2, 1536, 1536, 1536, 384, 0, 0, 0, 0, 0, 0, 1.0f);
    // out = LN(x + ff)
    ln_kernel<0><<<4096, blk, 0, stream>>>(x_f, ff_f, g2, be2, outMain, nullptr);
}